// Round 1
// baseline (384.077 us; speedup 1.0000x reference)
//
#include <hip/hip_runtime.h>

#define B_ 64
#define C_ 64
#define HW_ 256
#define OH_ 254
#define BINS_ 64
#define CH_ 4          // channels per block
#define NCOPY_ 4       // histogram privatization copies
#define TILE_ROWS_ 34
#define STEP_ROWS_ 32
#define NSTEPS_ 8
#define F_OUT_ 1000
#define KDIM_ 4096     // C_*BINS_

// ---------------------------------------------------------------------------
// Kernel 1: fused conv3x3 + ReLU + per-(b,c) min/max + 64-bin histogram.
// Grid: (16 chan-groups, 64 batch). Block: 256 threads (4 waves).
// Two passes over recomputed conv (cheaper than materializing 1 GB of y).
// Thread tiling: 64 col-groups x 4 cols, 4 row-groups x 8 rows (sliding
// 3x8 register window), 4 channels amortize each LDS window read.
// ---------------------------------------------------------------------------
__global__ __launch_bounds__(256, 4) void conv_hist_kernel(
    const float* __restrict__ x, const float* __restrict__ cw,
    const float* __restrict__ cb, float* __restrict__ feat)
{
    __shared__ float tile[TILE_ROWS_ * 256 + 8];
    __shared__ unsigned int hist[CH_ * BINS_ * NCOPY_];
    __shared__ float red_mn[4][CH_], red_mx[4][CH_];
    __shared__ float s_lo[CH_], s_sc[CH_];

    const int tid = threadIdx.x;
    const int b = blockIdx.y;
    const int c0 = blockIdx.x * CH_;
    const int g = tid & 63;        // column group (one wave = 64 groups)
    const int rg = tid >> 6;       // row group == wave id
    const int colbase = g << 2;
    const int lane = tid & 63;

    float wgt[CH_][9], bias[CH_];
#pragma unroll
    for (int ch = 0; ch < CH_; ++ch) {
#pragma unroll
        for (int j = 0; j < 9; ++j) wgt[ch][j] = cw[(c0 + ch) * 9 + j];
        bias[ch] = cb[c0 + ch];
    }

    const float* xb = x + (size_t)b * (HW_ * HW_);

    auto load_tile = [&](int R0) {
        for (int i = tid; i < TILE_ROWS_ * 64; i += 256) {
            int rl = i >> 6;
            int c4 = (i & 63) << 2;
            int rgl = R0 + rl;
            if (rgl < HW_) {
                float4 v = *(const float4*)(xb + rgl * 256 + c4);
                *(float4*)(tile + rl * 256 + c4) = v;
            }
        }
    };

    // -------- pass 1: min/max of raw conv+bias (relu applied at reduce) ----
    float mn[CH_], mx[CH_];
#pragma unroll
    for (int ch = 0; ch < CH_; ++ch) { mn[ch] = 3.402823466e38f; mx[ch] = -3.402823466e38f; }

    for (int step = 0; step < NSTEPS_; ++step) {
        const int R0 = step * STEP_ROWS_;
        __syncthreads();
        load_tile(R0);
        __syncthreads();
        const int rbase = rg * 8;
        float win[3][8];
        *(float4*)&win[0][0] = *(const float4*)(tile + (rbase + 0) * 256 + colbase);
        *(float4*)&win[0][4] = *(const float4*)(tile + (rbase + 0) * 256 + colbase + 4);
        *(float4*)&win[1][0] = *(const float4*)(tile + (rbase + 1) * 256 + colbase);
        *(float4*)&win[1][4] = *(const float4*)(tile + (rbase + 1) * 256 + colbase + 4);
#pragma unroll
        for (int rr = 0; rr < 8; ++rr) {
            const int w0 = rr % 3, w1 = (rr + 1) % 3, w2 = (rr + 2) % 3;
            *(float4*)&win[w2][0] = *(const float4*)(tile + (rbase + rr + 2) * 256 + colbase);
            *(float4*)&win[w2][4] = *(const float4*)(tile + (rbase + rr + 2) * 256 + colbase + 4);
            const int orow = R0 + rbase + rr;
            const bool rowok = orow < OH_;
#pragma unroll
            for (int ch = 0; ch < CH_; ++ch) {
#pragma unroll
                for (int cc = 0; cc < 4; ++cc) {
                    float v = bias[ch];
#pragma unroll
                    for (int kx = 0; kx < 3; ++kx) {
                        v = fmaf(win[w0][cc + kx], wgt[ch][kx], v);
                        v = fmaf(win[w1][cc + kx], wgt[ch][3 + kx], v);
                        v = fmaf(win[w2][cc + kx], wgt[ch][6 + kx], v);
                    }
                    if (rowok && (colbase + cc) < OH_) {
                        mn[ch] = fminf(mn[ch], v);
                        mx[ch] = fmaxf(mx[ch], v);
                    }
                }
            }
        }
    }

    // reduce min/max: wave shuffle then cross-wave via LDS
#pragma unroll
    for (int ch = 0; ch < CH_; ++ch) {
#pragma unroll
        for (int off = 32; off > 0; off >>= 1) {
            mn[ch] = fminf(mn[ch], __shfl_xor(mn[ch], off, 64));
            mx[ch] = fmaxf(mx[ch], __shfl_xor(mx[ch], off, 64));
        }
    }
    if (lane == 0) {
#pragma unroll
        for (int ch = 0; ch < CH_; ++ch) { red_mn[rg][ch] = mn[ch]; red_mx[rg][ch] = mx[ch]; }
    }
    for (int i = tid; i < CH_ * BINS_ * NCOPY_; i += 256) hist[i] = 0u;
    __syncthreads();
    if (tid < CH_) {
        float rmn = fminf(fminf(red_mn[0][tid], red_mn[1][tid]),
                          fminf(red_mn[2][tid], red_mn[3][tid]));
        float rmx = fmaxf(fmaxf(red_mx[0][tid], red_mx[1][tid]),
                          fmaxf(red_mx[2][tid], red_mx[3][tid]));
        float lo = fmaxf(rmn, 0.0f);   // min(relu(v)) == relu(min(v))
        float hi = fmaxf(rmx, 0.0f);
        if (hi == lo) { lo -= 1.0f; hi += 1.0f; }
        s_lo[tid] = lo;
        s_sc[tid] = 64.0f / (hi - lo);
    }
    __syncthreads();

    float lo_r[CH_], sc_r[CH_];
#pragma unroll
    for (int ch = 0; ch < CH_; ++ch) { lo_r[ch] = s_lo[ch]; sc_r[ch] = s_sc[ch]; }
    unsigned int cnt0[CH_] = {0u, 0u, 0u, 0u};

    // -------- pass 2: recompute conv, bin, LDS histogram ------------------
    for (int step = 0; step < NSTEPS_; ++step) {
        const int R0 = step * STEP_ROWS_;
        __syncthreads();
        load_tile(R0);
        __syncthreads();
        const int rbase = rg * 8;
        float win[3][8];
        *(float4*)&win[0][0] = *(const float4*)(tile + (rbase + 0) * 256 + colbase);
        *(float4*)&win[0][4] = *(const float4*)(tile + (rbase + 0) * 256 + colbase + 4);
        *(float4*)&win[1][0] = *(const float4*)(tile + (rbase + 1) * 256 + colbase);
        *(float4*)&win[1][4] = *(const float4*)(tile + (rbase + 1) * 256 + colbase + 4);
#pragma unroll
        for (int rr = 0; rr < 8; ++rr) {
            const int w0 = rr % 3, w1 = (rr + 1) % 3, w2 = (rr + 2) % 3;
            *(float4*)&win[w2][0] = *(const float4*)(tile + (rbase + rr + 2) * 256 + colbase);
            *(float4*)&win[w2][4] = *(const float4*)(tile + (rbase + rr + 2) * 256 + colbase + 4);
            const int orow = R0 + rbase + rr;
            const bool rowok = orow < OH_;
#pragma unroll
            for (int ch = 0; ch < CH_; ++ch) {
#pragma unroll
                for (int cc = 0; cc < 4; ++cc) {
                    float v = bias[ch];
#pragma unroll
                    for (int kx = 0; kx < 3; ++kx) {
                        v = fmaf(win[w0][cc + kx], wgt[ch][kx], v);
                        v = fmaf(win[w1][cc + kx], wgt[ch][3 + kx], v);
                        v = fmaf(win[w2][cc + kx], wgt[ch][6 + kx], v);
                    }
                    if (rowok && (colbase + cc) < OH_) {
                        float y = fmaxf(v, 0.0f);
                        float t = (y - lo_r[ch]) * sc_r[ch];
                        int bin = (int)t;           // t >= 0 always
                        bin = min(bin, 63);
                        if (bin == 0) cnt0[ch]++;   // ~53% of values: bin0 kept in reg
                        else atomicAdd(&hist[(ch * BINS_ + bin) * NCOPY_ + (tid & 3)], 1u);
                    }
                }
            }
        }
    }

#pragma unroll
    for (int ch = 0; ch < CH_; ++ch)
        if (cnt0[ch]) atomicAdd(&hist[(ch * BINS_) * NCOPY_ + (tid & 3)], cnt0[ch]);
    __syncthreads();

    // write feat[b][ (c0+ch)*64 + bin ] — all 256 threads, one entry each
    {
        int ch = tid >> 6, bin = tid & 63;
        unsigned int s = hist[tid * NCOPY_ + 0] + hist[tid * NCOPY_ + 1] +
                         hist[tid * NCOPY_ + 2] + hist[tid * NCOPY_ + 3];
        feat[(size_t)b * KDIM_ + (c0 + ch) * BINS_ + bin] = (float)s;
    }
}

// ---------------------------------------------------------------------------
// Kernel 2: out[64,1000] = feat[64,4096] @ head_w[1000,4096]^T + head_b
// 250 blocks x 4 N-cols; split-K=4 within block, LDS reduce.
// ---------------------------------------------------------------------------
__global__ __launch_bounds__(256) void head_gemm_kernel(
    const float* __restrict__ feat, const float* __restrict__ hw,
    const float* __restrict__ hb, float* __restrict__ out)
{
    __shared__ float red[256][5];
    const int tid = threadIdx.x;
    const int m = tid & 63;
    const int kq = tid >> 6;
    const int n0 = blockIdx.x * 4;

    float acc0 = 0.f, acc1 = 0.f, acc2 = 0.f, acc3 = 0.f;
    const float4* fp = (const float4*)(feat + (size_t)m * KDIM_ + kq * 1024);
    const float4* w0 = (const float4*)(hw + (size_t)(n0 + 0) * KDIM_ + kq * 1024);
    const float4* w1 = (const float4*)(hw + (size_t)(n0 + 1) * KDIM_ + kq * 1024);
    const float4* w2 = (const float4*)(hw + (size_t)(n0 + 2) * KDIM_ + kq * 1024);
    const float4* w3 = (const float4*)(hw + (size_t)(n0 + 3) * KDIM_ + kq * 1024);

#pragma unroll 4
    for (int i = 0; i < 256; ++i) {
        float4 f = fp[i];
        float4 a = w0[i]; acc0 += f.x * a.x + f.y * a.y + f.z * a.z + f.w * a.w;
        float4 b = w1[i]; acc1 += f.x * b.x + f.y * b.y + f.z * b.z + f.w * b.w;
        float4 c = w2[i]; acc2 += f.x * c.x + f.y * c.y + f.z * c.z + f.w * c.w;
        float4 d = w3[i]; acc3 += f.x * d.x + f.y * d.y + f.z * d.z + f.w * d.w;
    }
    red[tid][0] = acc0; red[tid][1] = acc1; red[tid][2] = acc2; red[tid][3] = acc3;
    __syncthreads();
    if (tid < 64) {
#pragma unroll
        for (int n = 0; n < 4; ++n) {
            float v = red[tid][n] + red[tid + 64][n] + red[tid + 128][n] +
                      red[tid + 192][n] + hb[n0 + n];
            out[(size_t)tid * F_OUT_ + n0 + n] = v;
        }
    }
}

extern "C" void kernel_launch(void* const* d_in, const int* in_sizes, int n_in,
                              void* d_out, int out_size, void* d_ws, size_t ws_size,
                              hipStream_t stream) {
    const float* x      = (const float*)d_in[0];
    const float* conv_w = (const float*)d_in[1];
    const float* conv_b = (const float*)d_in[2];
    const float* head_w = (const float*)d_in[3];
    const float* head_b = (const float*)d_in[4];
    float* out  = (float*)d_out;
    float* feat = (float*)d_ws;   // 64*4096 floats = 1 MB scratch

    conv_hist_kernel<<<dim3(16, 64), 256, 0, stream>>>(x, conv_w, conv_b, feat);
    head_gemm_kernel<<<250, 256, 0, stream>>>(feat, head_w, head_b, out);
}

// Round 3
// 374.448 us; speedup vs baseline: 1.0257x; 1.0257x over previous
//
#include <hip/hip_runtime.h>

#define HW_ 256
#define OH_ 254
#define BINS_ 64
#define CH_ 4          // channels per block
#define NCOPY_ 4       // histogram privatization copies
#define HSTRIDE_ 272   // (BINS_ + trash bin 64 + pad) * NCOPY_
#define TILE_ROWS_ 34
#define NSTEPS_ 8
#define F_OUT_ 1000
#define KDIM_ 4096

// ---------------------------------------------------------------------------
// Kernel 1: fused conv3x3 + per-(b,c) min/max + 64-bin histogram.
// Grid (16 chan-groups, 64 batch), 256 threads. Two conv passes (recompute
// is cheaper than 1 GB of y traffic). Per-lane predication removed:
//  - rg scalarized via readfirstlane -> row guards are scalar branches
//  - lane 63 covers cols 252..253; its cc=2,3 are garbage: pass1 substitutes
//    v0 (1 cndmask), pass2 redirects to trash bin 64 (1 cndmask)
//  - bin = (int)med3(fma(v,sc,-lo*sc), 0, 63)  [med3 clamp — (int) alone
//    does NOT clamp large-negative t; that was Round 2's LDS-corruption bug]
//  - bin0 never counted; reconstructed as 64516 - sum(bins 1..63)
// Writes feat TRANSPOSED k-quad-interleaved: featQ[(k>>2)*256 + b*4 + (k&3)]
// ---------------------------------------------------------------------------
__global__ __launch_bounds__(256, 4) void conv_hist_kernel(
    const float* __restrict__ x, const float* __restrict__ cw,
    const float* __restrict__ cb, float* __restrict__ featQ)
{
    __shared__ float tile[TILE_ROWS_ * 256 + 8];
    __shared__ unsigned int hist[CH_ * HSTRIDE_];
    __shared__ float red_mn[4][CH_], red_mx[4][CH_];
    __shared__ float s_sc[CH_], s_nls[CH_];

    const int tid = threadIdx.x;
    const int b = blockIdx.y;
    const int c0 = blockIdx.x * CH_;
    const int lane = tid & 63;
    const int rg = __builtin_amdgcn_readfirstlane(tid >> 6);  // wave id, scalar
    const int rbase = rg * 8;
    const int colbase = lane << 2;           // lane 63 -> 252
    const bool l63 = (lane == 63);

    float wgt[CH_][9], bias[CH_];
#pragma unroll
    for (int ch = 0; ch < CH_; ++ch) {
#pragma unroll
        for (int j = 0; j < 9; ++j) wgt[ch][j] = cw[(c0 + ch) * 9 + j];
        bias[ch] = cb[c0 + ch];
    }

    const float* xb = x + (size_t)b * (HW_ * HW_);

    auto load_tile = [&](int R0) {
        for (int i = tid; i < TILE_ROWS_ * 64; i += 256) {
            int rl = i >> 6;
            int c4 = (i & 63) << 2;
            int rgl = R0 + rl;
            if (rgl < HW_)
                *(float4*)(tile + rl * 256 + c4) = *(const float4*)(xb + rgl * 256 + c4);
        }
    };

    // conv of 4 columns for one channel from three window rows
    auto conv4 = [&](const float* r0, const float* r1, const float* r2,
                     int ch, float* vout) {
#pragma unroll
        for (int cc = 0; cc < 4; ++cc) {
            float v = bias[ch];
#pragma unroll
            for (int kx = 0; kx < 3; ++kx) {
                v = fmaf(r0[cc + kx], wgt[ch][kx], v);
                v = fmaf(r1[cc + kx], wgt[ch][3 + kx], v);
                v = fmaf(r2[cc + kx], wgt[ch][6 + kx], v);
            }
            vout[cc] = v;
        }
    };

    // ---------------- pass 1: min/max of conv+bias ------------------------
    float mn[CH_], mx[CH_];
#pragma unroll
    for (int ch = 0; ch < CH_; ++ch) { mn[ch] = 3.402823466e38f; mx[ch] = -3.402823466e38f; }

    for (int step = 0; step < NSTEPS_; ++step) {
        const int R0 = step * 32;
        __syncthreads();
        load_tile(R0);
        __syncthreads();
        float win[3][8];
        *(float4*)&win[0][0] = *(const float4*)(tile + (rbase + 0) * 256 + colbase);
        *(float4*)&win[0][4] = *(const float4*)(tile + (rbase + 0) * 256 + colbase + 4);
        *(float4*)&win[1][0] = *(const float4*)(tile + (rbase + 1) * 256 + colbase);
        *(float4*)&win[1][4] = *(const float4*)(tile + (rbase + 1) * 256 + colbase + 4);
#pragma unroll
        for (int rr = 0; rr < 8; ++rr) {
            const int w0 = rr % 3, w1 = (rr + 1) % 3, w2 = (rr + 2) % 3;
            *(float4*)&win[w2][0] = *(const float4*)(tile + (rbase + rr + 2) * 256 + colbase);
            *(float4*)&win[w2][4] = *(const float4*)(tile + (rbase + rr + 2) * 256 + colbase + 4);
            if (R0 + rbase + rr < OH_) {      // scalar guard (rg scalarized)
#pragma unroll
                for (int ch = 0; ch < CH_; ++ch) {
                    float v[4];
                    conv4(win[w0], win[w1], win[w2], ch, v);
                    float v2m = l63 ? v[0] : v[2];   // lane63 cc2,3 invalid: dup v0
                    float v3m = l63 ? v[0] : v[3];
                    mn[ch] = fminf(fminf(mn[ch], v[0]), v[1]);   // -> v_min3
                    mn[ch] = fminf(fminf(mn[ch], v2m), v3m);
                    mx[ch] = fmaxf(fmaxf(mx[ch], v[0]), v[1]);
                    mx[ch] = fmaxf(fmaxf(mx[ch], v2m), v3m);
                }
            }
        }
    }

    // wave shuffle reduce, then cross-wave via LDS
#pragma unroll
    for (int ch = 0; ch < CH_; ++ch) {
#pragma unroll
        for (int off = 32; off > 0; off >>= 1) {
            mn[ch] = fminf(mn[ch], __shfl_xor(mn[ch], off, 64));
            mx[ch] = fmaxf(mx[ch], __shfl_xor(mx[ch], off, 64));
        }
    }
    if (lane == 0) {
#pragma unroll
        for (int ch = 0; ch < CH_; ++ch) { red_mn[rg][ch] = mn[ch]; red_mx[rg][ch] = mx[ch]; }
    }
    for (int i = tid; i < CH_ * HSTRIDE_; i += 256) hist[i] = 0u;
    __syncthreads();
    if (tid < CH_) {
        float rmn = fminf(fminf(red_mn[0][tid], red_mn[1][tid]),
                          fminf(red_mn[2][tid], red_mn[3][tid]));
        float rmx = fmaxf(fmaxf(red_mx[0][tid], red_mx[1][tid]),
                          fmaxf(red_mx[2][tid], red_mx[3][tid]));
        float lo = fmaxf(rmn, 0.0f);   // relu(min) == min(relu)
        float hi = fmaxf(rmx, 0.0f);
        if (hi == lo) { lo -= 1.0f; hi += 1.0f; }
        float sc = 64.0f / (hi - lo);
        s_sc[tid] = sc;
        s_nls[tid] = -lo * sc;
    }
    __syncthreads();

    float scr[CH_], nlsr[CH_];
    int hb4[CH_];
#pragma unroll
    for (int ch = 0; ch < CH_; ++ch) {
        scr[ch] = s_sc[ch];
        nlsr[ch] = s_nls[ch];
        hb4[ch] = ch * HSTRIDE_ + (tid & 3);
    }

    // bin = clamp(fma(v,sc,-lo*sc), 0, 63) via v_med3_f32, then cvt.
    // relu itself is subsumed: v<0 can only occur when lo==0, and the
    // clamp maps its (negative) t to bin 0 — same as relu would.
    auto binop = [&](float v, int ch, bool redirect) {
        float t = fmaf(v, scr[ch], nlsr[ch]);
        t = fminf(fmaxf(t, 0.0f), 63.0f);     // v_med3 clamp — REQUIRED
        int bin = (int)t;
        if (redirect) bin = l63 ? 64 : bin;   // trash slot for invalid cols
        if (bin != 0) atomicAdd(&hist[hb4[ch] + (bin << 2)], 1u);
    };

    // ---------------- pass 2: recompute conv, bin, histogram --------------
    for (int step = 0; step < NSTEPS_; ++step) {
        const int R0 = step * 32;
        __syncthreads();
        load_tile(R0);
        __syncthreads();
        float win[3][8];
        *(float4*)&win[0][0] = *(const float4*)(tile + (rbase + 0) * 256 + colbase);
        *(float4*)&win[0][4] = *(const float4*)(tile + (rbase + 0) * 256 + colbase + 4);
        *(float4*)&win[1][0] = *(const float4*)(tile + (rbase + 1) * 256 + colbase);
        *(float4*)&win[1][4] = *(const float4*)(tile + (rbase + 1) * 256 + colbase + 4);
#pragma unroll
        for (int rr = 0; rr < 8; ++rr) {
            const int w0 = rr % 3, w1 = (rr + 1) % 3, w2 = (rr + 2) % 3;
            *(float4*)&win[w2][0] = *(const float4*)(tile + (rbase + rr + 2) * 256 + colbase);
            *(float4*)&win[w2][4] = *(const float4*)(tile + (rbase + rr + 2) * 256 + colbase + 4);
            if (R0 + rbase + rr < OH_) {
#pragma unroll
                for (int ch = 0; ch < CH_; ++ch) {
                    float v[4];
                    conv4(win[w0], win[w1], win[w2], ch, v);
                    binop(v[0], ch, false);
                    binop(v[1], ch, false);
                    binop(v[2], ch, true);
                    binop(v[3], ch, true);
                }
            }
        }
    }
    __syncthreads();

    // epilogue: fold copies, reconstruct bin0 analytically, write featQ
    unsigned int* sums = (unsigned int*)tile;   // tile is dead now
    {
        int ch = tid >> 6, bin = tid & 63;
        unsigned int s = hist[ch * HSTRIDE_ + (bin << 2) + 0] +
                         hist[ch * HSTRIDE_ + (bin << 2) + 1] +
                         hist[ch * HSTRIDE_ + (bin << 2) + 2] +
                         hist[ch * HSTRIDE_ + (bin << 2) + 3];
        sums[tid] = s;
    }
    __syncthreads();
    {
        int ch = tid >> 6, bin = tid & 63;
        unsigned int s = sums[tid];
        if (bin == 0) {
            unsigned int tot = 0;
            for (int j = 1; j < 64; ++j) tot += sums[tid + j];
            s = 64516u - tot;                 // 254*254 valid values
        }
        int k = (c0 + ch) * BINS_ + bin;
        featQ[(k >> 2) * 256 + (b << 2) + (k & 3)] = (float)s;
    }
}

// ---------------------------------------------------------------------------
// Kernel 2: out[64,1000] = feat @ head_w^T + head_b, feat in featQ layout.
// 125 blocks x 4 waves; wave handles 2 n-cols, lane = batch m.
// featQ float4 loads fully coalesced; head_w loads wave-uniform.
// ---------------------------------------------------------------------------
__global__ __launch_bounds__(256) void head_kernel(
    const float* __restrict__ featQ, const float* __restrict__ hw,
    const float* __restrict__ hb, float* __restrict__ out)
{
    const int m = threadIdx.x & 63;
    const int w = __builtin_amdgcn_readfirstlane(threadIdx.x >> 6);
    const int n0 = (blockIdx.x * 4 + w) * 2;
    const float* w0 = hw + (size_t)n0 * KDIM_;
    const float* w1 = w0 + KDIM_;

    float a0 = 0.f, a1 = 0.f;
#pragma unroll 4
    for (int kq = 0; kq < 1024; ++kq) {
        float4 f = *(const float4*)(featQ + (kq << 8) + (m << 2));
        float4 u = *(const float4*)(w0 + (kq << 2));
        float4 v = *(const float4*)(w1 + (kq << 2));
        a0 += f.x * u.x + f.y * u.y + f.z * u.z + f.w * u.w;
        a1 += f.x * v.x + f.y * v.y + f.z * v.z + f.w * v.w;
    }
    out[m * F_OUT_ + n0]     = a0 + hb[n0];
    out[m * F_OUT_ + n0 + 1] = a1 + hb[n0 + 1];
}

extern "C" void kernel_launch(void* const* d_in, const int* in_sizes, int n_in,
                              void* d_out, int out_size, void* d_ws, size_t ws_size,
                              hipStream_t stream) {
    const float* x      = (const float*)d_in[0];
    const float* conv_w = (const float*)d_in[1];
    const float* conv_b = (const float*)d_in[2];
    const float* head_w = (const float*)d_in[3];
    const float* head_b = (const float*)d_in[4];
    float* out   = (float*)d_out;
    float* featQ = (float*)d_ws;   // 4096*64 floats = 1 MB scratch

    conv_hist_kernel<<<dim3(16, 64), 256, 0, stream>>>(x, conv_w, conv_b, featQ);
    head_kernel<<<125, 256, 0, stream>>>(featQ, head_w, head_b, out);
}

// Round 4
// 316.206 us; speedup vs baseline: 1.2146x; 1.1842x over previous
//
#include <hip/hip_runtime.h>

#define HW_ 256
#define OH_ 254
#define BINS_ 64
#define CH_ 4          // channels per block (2 pk channel-pairs)
#define HSTRIDE_ 272   // (BINS_ + trash bin 64 + pad) * NCOPY(4)
#define TILE_ROWS_ 34
#define NSTEPS_ 8
#define F_OUT_ 1000
#define KDIM_ 4096

typedef float f32x2 __attribute__((ext_vector_type(2)));

// ---------------------------------------------------------------------------
// Kernel 1: fused conv3x3 + per-(b,c) min/max + 64-bin histogram.
// Grid (16 chan-groups, 64 batch), 256 threads. Two conv passes.
// Round-4 change: conv computed with packed fp32 (v_pk_fma_f32) over
// CHANNEL pairs: acc{ch0,ch1} += {x,x}*{w[ch0][j],w[ch1][j]} — weights pair
// naturally (no broadcast materialization), x-splat foldable to op_sel.
// Halves the conv instruction count on an instruction-issue-bound kernel.
// Everything else identical to the verified Round-3 structure:
//  - rg scalarized -> scalar row guards; lane63 cols 2,3 redirected
//  - bin = (int)med3(fma(v,sc,-lo*sc),0,63); bin0 reconstructed analytically
//  - featQ transposed k-quad-interleaved: featQ[(k>>2)*256 + b*4 + (k&3)]
// ---------------------------------------------------------------------------
__global__ __launch_bounds__(256, 4) void conv_hist_kernel(
    const float* __restrict__ x, const float* __restrict__ cw,
    const float* __restrict__ cb, float* __restrict__ featQ)
{
    __shared__ float tile[TILE_ROWS_ * 256 + 8];
    __shared__ unsigned int hist[CH_ * HSTRIDE_];
    __shared__ float red_mn[4][CH_], red_mx[4][CH_];
    __shared__ float s_sc[CH_], s_nls[CH_];

    const int tid = threadIdx.x;
    const int b = blockIdx.y;
    const int c0 = blockIdx.x * CH_;
    const int lane = tid & 63;
    const int rg = __builtin_amdgcn_readfirstlane(tid >> 6);  // wave id, scalar
    const int rbase = rg * 8;
    const int colbase = lane << 2;           // lane 63 -> 252
    const bool l63 = (lane == 63);

    // weights as channel-pairs: wp[p][j] = {w[2p][j], w[2p+1][j]}
    f32x2 wp[2][9], bp2[2];
#pragma unroll
    for (int p = 0; p < 2; ++p) {
#pragma unroll
        for (int j = 0; j < 9; ++j) {
            wp[p][j][0] = cw[(c0 + 2 * p) * 9 + j];
            wp[p][j][1] = cw[(c0 + 2 * p + 1) * 9 + j];
        }
        bp2[p][0] = cb[c0 + 2 * p];
        bp2[p][1] = cb[c0 + 2 * p + 1];
    }

    const float* xb = x + (size_t)b * (HW_ * HW_);

    auto load_tile = [&](int R0) {
        for (int i = tid; i < TILE_ROWS_ * 64; i += 256) {
            int rl = i >> 6;
            int c4 = (i & 63) << 2;
            int rgl = R0 + rl;
            if (rgl < HW_)
                *(float4*)(tile + rl * 256 + c4) = *(const float4*)(xb + rgl * 256 + c4);
        }
    };

    // conv of 4 columns x 2 channel-pairs from three window rows (pk fma)
    auto conv8 = [&](const float* r0, const float* r1, const float* r2,
                     f32x2 acc[2][4]) {
#pragma unroll
        for (int c = 0; c < 4; ++c) {
#pragma unroll
            for (int p = 0; p < 2; ++p) acc[p][c] = bp2[p];
#pragma unroll
            for (int kx = 0; kx < 3; ++kx) {
                float x0 = r0[c + kx], x1 = r1[c + kx], x2 = r2[c + kx];
#pragma unroll
                for (int p = 0; p < 2; ++p) {
                    acc[p][c] = __builtin_elementwise_fma((f32x2){x0, x0}, wp[p][kx],     acc[p][c]);
                    acc[p][c] = __builtin_elementwise_fma((f32x2){x1, x1}, wp[p][3 + kx], acc[p][c]);
                    acc[p][c] = __builtin_elementwise_fma((f32x2){x2, x2}, wp[p][6 + kx], acc[p][c]);
                }
            }
        }
    };

    // ---------------- pass 1: min/max of conv+bias ------------------------
    float mn[CH_], mx[CH_];
#pragma unroll
    for (int ch = 0; ch < CH_; ++ch) { mn[ch] = 3.402823466e38f; mx[ch] = -3.402823466e38f; }

    for (int step = 0; step < NSTEPS_; ++step) {
        const int R0 = step * 32;
        __syncthreads();
        load_tile(R0);
        __syncthreads();
        float win[3][8];
        *(float4*)&win[0][0] = *(const float4*)(tile + (rbase + 0) * 256 + colbase);
        *(float4*)&win[0][4] = *(const float4*)(tile + (rbase + 0) * 256 + colbase + 4);
        *(float4*)&win[1][0] = *(const float4*)(tile + (rbase + 1) * 256 + colbase);
        *(float4*)&win[1][4] = *(const float4*)(tile + (rbase + 1) * 256 + colbase + 4);
#pragma unroll
        for (int rr = 0; rr < 8; ++rr) {
            const int w0 = rr % 3, w1 = (rr + 1) % 3, w2 = (rr + 2) % 3;
            *(float4*)&win[w2][0] = *(const float4*)(tile + (rbase + rr + 2) * 256 + colbase);
            *(float4*)&win[w2][4] = *(const float4*)(tile + (rbase + rr + 2) * 256 + colbase + 4);
            if (R0 + rbase + rr < OH_) {      // scalar guard (rg scalarized)
                f32x2 acc[2][4];
                conv8(win[w0], win[w1], win[w2], acc);
#pragma unroll
                for (int p = 0; p < 2; ++p) {
#pragma unroll
                    for (int h = 0; h < 2; ++h) {
                        const int ch = 2 * p + h;
                        float v0 = acc[p][0][h], v1 = acc[p][1][h];
                        float v2 = acc[p][2][h], v3 = acc[p][3][h];
                        float v2m = l63 ? v0 : v2;   // lane63 cc2,3 invalid
                        float v3m = l63 ? v0 : v3;
                        mn[ch] = fminf(fminf(mn[ch], v0), v1);
                        mn[ch] = fminf(fminf(mn[ch], v2m), v3m);
                        mx[ch] = fmaxf(fmaxf(mx[ch], v0), v1);
                        mx[ch] = fmaxf(fmaxf(mx[ch], v2m), v3m);
                    }
                }
            }
        }
    }

    // wave shuffle reduce, then cross-wave via LDS
#pragma unroll
    for (int ch = 0; ch < CH_; ++ch) {
#pragma unroll
        for (int off = 32; off > 0; off >>= 1) {
            mn[ch] = fminf(mn[ch], __shfl_xor(mn[ch], off, 64));
            mx[ch] = fmaxf(mx[ch], __shfl_xor(mx[ch], off, 64));
        }
    }
    if (lane == 0) {
#pragma unroll
        for (int ch = 0; ch < CH_; ++ch) { red_mn[rg][ch] = mn[ch]; red_mx[rg][ch] = mx[ch]; }
    }
    for (int i = tid; i < CH_ * HSTRIDE_; i += 256) hist[i] = 0u;
    __syncthreads();
    if (tid < CH_) {
        float rmn = fminf(fminf(red_mn[0][tid], red_mn[1][tid]),
                          fminf(red_mn[2][tid], red_mn[3][tid]));
        float rmx = fmaxf(fmaxf(red_mx[0][tid], red_mx[1][tid]),
                          fmaxf(red_mx[2][tid], red_mx[3][tid]));
        float lo = fmaxf(rmn, 0.0f);   // relu(min) == min(relu)
        float hi = fmaxf(rmx, 0.0f);
        if (hi == lo) { lo -= 1.0f; hi += 1.0f; }
        float sc = 64.0f / (hi - lo);
        s_sc[tid] = sc;
        s_nls[tid] = -lo * sc;
    }
    __syncthreads();

    f32x2 scp[2], nlsp[2];
    int hb4[CH_];
#pragma unroll
    for (int p = 0; p < 2; ++p) {
        scp[p][0] = s_sc[2 * p];     scp[p][1] = s_sc[2 * p + 1];
        nlsp[p][0] = s_nls[2 * p];   nlsp[p][1] = s_nls[2 * p + 1];
    }
#pragma unroll
    for (int ch = 0; ch < CH_; ++ch) hb4[ch] = ch * HSTRIDE_ + (tid & 3);

    // ---------------- pass 2: recompute conv, bin, histogram --------------
    for (int step = 0; step < NSTEPS_; ++step) {
        const int R0 = step * 32;
        __syncthreads();
        load_tile(R0);
        __syncthreads();
        float win[3][8];
        *(float4*)&win[0][0] = *(const float4*)(tile + (rbase + 0) * 256 + colbase);
        *(float4*)&win[0][4] = *(const float4*)(tile + (rbase + 0) * 256 + colbase + 4);
        *(float4*)&win[1][0] = *(const float4*)(tile + (rbase + 1) * 256 + colbase);
        *(float4*)&win[1][4] = *(const float4*)(tile + (rbase + 1) * 256 + colbase + 4);
#pragma unroll
        for (int rr = 0; rr < 8; ++rr) {
            const int w0 = rr % 3, w1 = (rr + 1) % 3, w2 = (rr + 2) % 3;
            *(float4*)&win[w2][0] = *(const float4*)(tile + (rbase + rr + 2) * 256 + colbase);
            *(float4*)&win[w2][4] = *(const float4*)(tile + (rbase + rr + 2) * 256 + colbase + 4);
            if (R0 + rbase + rr < OH_) {
                f32x2 acc[2][4];
                conv8(win[w0], win[w1], win[w2], acc);
#pragma unroll
                for (int c = 0; c < 4; ++c) {
#pragma unroll
                    for (int p = 0; p < 2; ++p) {
                        f32x2 t2 = __builtin_elementwise_fma(acc[p][c], scp[p], nlsp[p]);
#pragma unroll
                        for (int h = 0; h < 2; ++h) {
                            float t = fminf(fmaxf(t2[h], 0.0f), 63.0f);  // v_med3
                            int bin = (int)t;
                            if (c >= 2) bin = l63 ? 64 : bin;   // trash slot
                            if (bin != 0)
                                atomicAdd(&hist[hb4[2 * p + h] + (bin << 2)], 1u);
                        }
                    }
                }
            }
        }
    }
    __syncthreads();

    // epilogue: fold copies, reconstruct bin0 analytically, write featQ
    unsigned int* sums = (unsigned int*)tile;   // tile is dead now
    {
        int ch = tid >> 6, bin = tid & 63;
        unsigned int s = hist[ch * HSTRIDE_ + (bin << 2) + 0] +
                         hist[ch * HSTRIDE_ + (bin << 2) + 1] +
                         hist[ch * HSTRIDE_ + (bin << 2) + 2] +
                         hist[ch * HSTRIDE_ + (bin << 2) + 3];
        sums[tid] = s;
    }
    __syncthreads();
    {
        int ch = tid >> 6, bin = tid & 63;
        unsigned int s = sums[tid];
        if (bin == 0) {
            unsigned int tot = 0;
            for (int j = 1; j < 64; ++j) tot += sums[tid + j];
            s = 64516u - tot;                 // 254*254 valid values
        }
        int k = (c0 + ch) * BINS_ + bin;
        featQ[(k >> 2) * 256 + (b << 2) + (k & 3)] = (float)s;
    }
}

// ---------------------------------------------------------------------------
// Kernel 2: out[64,1000] = feat @ head_w^T + head_b, feat in featQ layout.
// 250 blocks x 8 waves: 4 n-cols per block, split-K=2 per col (2000 waves
// total — Round 3's 500 waves left half the SIMDs idle, latency-exposed).
// ---------------------------------------------------------------------------
__global__ __launch_bounds__(512) void head_kernel(
    const float* __restrict__ featQ, const float* __restrict__ hw,
    const float* __restrict__ hb, float* __restrict__ out)
{
    __shared__ float red[4][64];
    const int tid = threadIdx.x;
    const int m = tid & 63;
    const int w = __builtin_amdgcn_readfirstlane(tid >> 6);  // 0..7
    const int nl = w >> 1;          // col within block
    const int kh = w & 1;           // K half
    const int n = blockIdx.x * 4 + nl;

    const float* wrow  = hw + (size_t)n * KDIM_ + kh * 2048;
    const float* fbase = featQ + (kh * 512) * 256 + (m << 2);

    float a = 0.f;
#pragma unroll 4
    for (int kq = 0; kq < 512; ++kq) {
        float4 f = *(const float4*)(fbase + (kq << 8));
        float4 u = *(const float4*)(wrow + (kq << 2));
        a += f.x * u.x + f.y * u.y + f.z * u.z + f.w * u.w;
    }
    if (kh == 0) red[nl][m] = a;
    __syncthreads();
    if (kh == 1) out[(size_t)m * F_OUT_ + n] = a + red[nl][m] + hb[n];
}

extern "C" void kernel_launch(void* const* d_in, const int* in_sizes, int n_in,
                              void* d_out, int out_size, void* d_ws, size_t ws_size,
                              hipStream_t stream) {
    const float* x      = (const float*)d_in[0];
    const float* conv_w = (const float*)d_in[1];
    const float* conv_b = (const float*)d_in[2];
    const float* head_w = (const float*)d_in[3];
    const float* head_b = (const float*)d_in[4];
    float* out   = (float*)d_out;
    float* featQ = (float*)d_ws;   // 4096*64 floats = 1 MB scratch

    conv_hist_kernel<<<dim3(16, 64), 256, 0, stream>>>(x, conv_w, conv_b, featQ);
    head_kernel<<<250, 512, 0, stream>>>(featQ, head_w, head_b, out);
}

// Round 5
// 252.380 us; speedup vs baseline: 1.5218x; 1.2529x over previous
//
#include <hip/hip_runtime.h>

// ---------------------------------------------------------------------------
// MFMA-based conv3x3(1->64) + per-(b,och) min/max + 64-bin histogram + head.
//
// conv as 32x32x16 bf16 MFMA: D[m=pixel-row][n=och] = A[m][k] * B[k][n],
//   k = dr*4 + dc (dr 0..2, dc 0..2 used; dc=3 and dr=3 slots zero-weighted).
// Split precision: x = xh + xl (bf16 pair), w = wh + wl;
//   conv = xh*wh + xl*wh + xh*wl  (3 MFMAs; dropped xl*wl ~ 2^-18 rel).
// Layouts (learn_hip-verified conventions):
//   A: m=lane&31, k=(lane>>5)*8+j (j=0..7 ascending through 4 VGPRs)
//   B: n=lane&31, k=(lane>>5)*8+j
//   C: col(n)=lane&31, row(m)=(reg&3)+8*(reg>>2)+4*(lane>>5)
// Input staged in LDS column-major t32[col][row] as packed {lo16|hi16} bf16
//   (4B/pixel -> aligned dword reads at any col; v_perm extracts hi/lo runs).
// ---------------------------------------------------------------------------

typedef short bf16x8 __attribute__((ext_vector_type(8)));
typedef float f32x16 __attribute__((ext_vector_type(16)));

#define TPITCH 35      // padded row-dim (col-major), breaks bank aliasing
#define TROWS 34
#define F_OUT_ 1000
#define KDIM_ 4096

__device__ __forceinline__ unsigned f2bf(float f) {   // RNE f32 -> bf16 bits
    unsigned u = __float_as_uint(f);
    return (u + 0x7FFFu + ((u >> 16) & 1u)) >> 16;
}
__device__ __forceinline__ float bf2f(unsigned h) { return __uint_as_float(h << 16); }

union FragU { uint4 u; bf16x8 v; };

template<int PASS>
__global__ __launch_bounds__(512, 4) void conv_mfma_kernel(
    const float* __restrict__ x, const float* __restrict__ cw,
    const float* __restrict__ cb, float* __restrict__ featQ,
    float* __restrict__ mnbuf, float* __restrict__ mxbuf)
{
    __shared__ unsigned t32[256 * TPITCH];     // 35840 B
    __shared__ unsigned hist[32 * 65 * 2];     // 16640 B (PASS2; 65th = trash)
    __shared__ float wmn[8][32], wmx[8][32];   // PASS1 reduce

    const int tid = threadIdx.x;
    const int lane = tid & 63;
    const int w = __builtin_amdgcn_readfirstlane(tid >> 6);   // wave 0..7
    const int b = blockIdx.x;                  // batch
    const int ob = blockIdx.y * 32;            // och base (0 or 32)
    const int seg = blockIdx.z;                // row segment (64 rows each)
    const int mrow = lane & 31;                // A m-index / B n-index
    const int kg = lane >> 5;                  // k-group 0/1

    if (PASS == 1) {   // zero featQ: 512 blocks x 512 floats = 256K exactly
        int z = (seg * 2 + blockIdx.y) * 64 + b;
        featQ[z * 512 + tid] = 0.f;
    }

    // ---- B fragments (wh, wl) + bias C-fragment, per lane (n = ob+mrow) ----
    const int och = ob + mrow;
    float wf[9];
#pragma unroll
    for (int t = 0; t < 9; ++t) wf[t] = cw[och * 9 + t];
    unsigned hh[8], ll[8];
#pragma unroll
    for (int j = 0; j < 8; ++j) {
        int k = kg * 8 + j, dr = k >> 2, dc = k & 3;
        float wv = (dr < 3 && dc < 3) ? wf[dr * 3 + dc] : 0.f;
        unsigned h = f2bf(wv);
        hh[j] = h;
        ll[j] = f2bf(wv - bf2f(h));
    }
    FragU bwh, bwl;
    bwh.u = make_uint4(hh[0] | (hh[1] << 16), hh[2] | (hh[3] << 16),
                       hh[4] | (hh[5] << 16), hh[6] | (hh[7] << 16));
    bwl.u = make_uint4(ll[0] | (ll[1] << 16), ll[2] | (ll[3] << 16),
                       ll[4] | (ll[5] << 16), ll[6] | (ll[7] << 16));
    const float bb = cb[och];
    f32x16 cbias;
#pragma unroll
    for (int r = 0; r < 16; ++r) cbias[r] = bb;

    // ---- PASS2: per-lane bin transform from K1's global min/max ----
    float sc = 0.f, nls = 0.f;
    if (PASS == 2) {
        float rmn = 3.402823466e38f, rmx = -3.402823466e38f;
#pragma unroll
        for (int s = 0; s < 4; ++s) {
            rmn = fminf(rmn, mnbuf[((b * 64 + och) << 2) | s]);
            rmx = fmaxf(rmx, mxbuf[((b * 64 + och) << 2) | s]);
        }
        float lo = fmaxf(rmn, 0.f);    // relu(min) == min(relu)
        float hi = fmaxf(rmx, 0.f);
        if (hi == lo) { lo -= 1.f; hi += 1.f; }
        sc = 64.f / (hi - lo);
        nls = -lo * sc;
        for (int i = tid; i < 32 * 65 * 2; i += 512) hist[i] = 0u;
    }
    const int histbase = mrow * 130 + kg;      // (och*65 + bin)*2 + copy(kg)
    float mn = 3.402823466e38f, mx = -3.402823466e38f;

    const float* xb = x + (size_t)b * 65536;

#pragma unroll 1
    for (int job = 0; job < 2; ++job) {
        const int r0 = seg * 64 + job * 32;    // output rows r0..r0+31
        const int vlim = min(32, 254 - r0);    // valid rows this job (30 tail)
        __syncthreads();
        // stage input rows r0..r0+33 as packed bf16 {lo|hi}, col-major
        for (int i = tid; i < TROWS * 256; i += 512) {
            int lrow = i >> 8, col = i & 255;
            int grow = r0 + lrow;
            float v = (grow < 256) ? xb[grow * 256 + col] : 0.f;
            unsigned h = f2bf(v);
            unsigned l = f2bf(v - bf2f(h));
            t32[col * TPITCH + lrow] = (l << 16) | h;
        }
        __syncthreads();
        const int cbase = w * 32;
        const int cend = min(cbase + 32, 254);
        const unsigned* tb = t32 + mrow;
#pragma unroll 1
        for (int c = cbase; c < cend; ++c) {
            const unsigned* p0 = tb + c * TPITCH;
            unsigned Ar0 = p0[0],            Ar1 = p0[1],            Ar2 = p0[2];
            unsigned Br0 = p0[TPITCH],       Br1 = p0[TPITCH + 1],   Br2 = p0[TPITCH + 2];
            unsigned Cr0 = p0[2 * TPITCH],   Cr1 = p0[2 * TPITCH + 1], Cr2 = p0[2 * TPITCH + 2];
            // hi pairs {xh[c],xh[c+1]} per row; lo pairs likewise
            unsigned ph0 = __builtin_amdgcn_perm(Br0, Ar0, 0x05040100u);
            unsigned ph1 = __builtin_amdgcn_perm(Br1, Ar1, 0x05040100u);
            unsigned ph2 = __builtin_amdgcn_perm(Br2, Ar2, 0x05040100u);
            unsigned pl0 = __builtin_amdgcn_perm(Br0, Ar0, 0x07060302u);
            unsigned pl1 = __builtin_amdgcn_perm(Br1, Ar1, 0x07060302u);
            unsigned pl2 = __builtin_amdgcn_perm(Br2, Ar2, 0x07060302u);
            // {xh[c+2], junk} is fine: the junk slot's weight is 0
            FragU ah, al;
            ah.u = kg ? make_uint4(ph2, Cr2, 0u, 0u)
                      : make_uint4(ph0, Cr0, ph1, Cr1);
            al.u = kg ? make_uint4(pl2, Cr2 >> 16, 0u, 0u)
                      : make_uint4(pl0, Cr0 >> 16, pl1, Cr1 >> 16);
            f32x16 acc = __builtin_amdgcn_mfma_f32_32x32x16_bf16(ah.v, bwh.v, cbias, 0, 0, 0);
            acc = __builtin_amdgcn_mfma_f32_32x32x16_bf16(al.v, bwh.v, acc, 0, 0, 0);
            acc = __builtin_amdgcn_mfma_f32_32x32x16_bf16(ah.v, bwl.v, acc, 0, 0, 0);
            if (PASS == 1) {
                if (vlim >= 32) {
#pragma unroll
                    for (int r = 0; r < 16; r += 2) {
                        mn = fminf(fminf(acc[r], acc[r + 1]), mn);   // v_min3
                        mx = fmaxf(fmaxf(acc[r], acc[r + 1]), mx);
                    }
                } else {
#pragma unroll
                    for (int r = 0; r < 16; ++r) {
                        int crow = (r & 3) + 8 * (r >> 2) + 4 * kg;
                        float v = (crow < vlim) ? acc[r] : acc[0];  // acc[0] always valid
                        mn = fminf(mn, v); mx = fmaxf(mx, v);
                    }
                }
            } else {
#pragma unroll
                for (int r = 0; r < 16; ++r) {
                    float t = fmaf(acc[r], sc, nls);
                    t = fminf(fmaxf(t, 0.f), 63.f);    // v_med3 clamp (R2 lesson)
                    int bin = (int)t;
                    if (vlim < 32) {
                        int crow = (r & 3) + 8 * (r >> 2) + 4 * kg;
                        if (crow >= vlim) bin = 64;    // trash slot
                    }
                    if (bin != 0) atomicAdd(&hist[histbase + bin * 2], 1u);
                }
            }
        }
    }

    if (PASS == 1) {
        // combine kg halves, then cross-wave, then store per-seg min/max
        mn = fminf(mn, __shfl_xor(mn, 32, 64));
        mx = fmaxf(mx, __shfl_xor(mx, 32, 64));
        if (lane < 32) { wmn[w][lane] = mn; wmx[w][lane] = mx; }
        __syncthreads();
        if (tid < 32) {
            float a = wmn[0][tid], c = wmx[0][tid];
            for (int i = 1; i < 8; ++i) {
                a = fminf(a, wmn[i][tid]); c = fmaxf(c, wmx[i][tid]);
            }
            int o = ob + tid;
            mnbuf[((b * 64 + o) << 2) | seg] = a;
            mxbuf[((b * 64 + o) << 2) | seg] = c;
        }
    } else {
        __syncthreads();
        const int validpx = (seg == 3 ? 62 : 64) * 254;
        for (int i = tid; i < 2048; i += 512) {
            int o = i >> 6, bin = i & 63;
            float cnt;
            if (bin == 0) {   // analytic bin0 = validpx - sum(bins 1..63)
                unsigned s = 0;
                for (int j = 1; j < 64; ++j)
                    s += hist[(o * 65 + j) * 2] + hist[(o * 65 + j) * 2 + 1];
                cnt = (float)(validpx - (int)s);
            } else {
                cnt = (float)(hist[(o * 65 + bin) * 2] + hist[(o * 65 + bin) * 2 + 1]);
            }
            int k = ((ob + o) << 6) | bin;
            // featQ quad layout: featQ[(k>>2)*256 + b*4 + (k&3)]
            atomicAdd(&featQ[((k >> 2) << 8) | (b << 2) | (k & 3)], cnt);
        }
    }
}

// ---------------------------------------------------------------------------
// Head: out[64,1000] = feat @ head_w^T + head_b. 250 blocks x 4 cols;
// 4 waves split K (each 1024) -> featQ read once per block (250 MB L2 total,
// vs R4's 1 GB per-wave re-read). Weights wave-uniform (s_load streams).
// ---------------------------------------------------------------------------
__global__ __launch_bounds__(256) void head_kernel(
    const float* __restrict__ featQ, const float* __restrict__ hw,
    const float* __restrict__ hb, float* __restrict__ out)
{
    __shared__ float red[4][4][64];
    const int tid = threadIdx.x;
    const int m = tid & 63;
    const int kh = __builtin_amdgcn_readfirstlane(tid >> 6);   // K quarter
    const int n0 = blockIdx.x * 4;
    const float* w0 = hw + (size_t)n0 * KDIM_ + kh * 1024;
    const float* w1 = w0 + KDIM_;
    const float* w2 = w1 + KDIM_;
    const float* w3 = w2 + KDIM_;
    const float* fb = featQ + kh * 256 * 256 + (m << 2);

    float a0 = 0.f, a1 = 0.f, a2 = 0.f, a3 = 0.f;
#pragma unroll 4
    for (int kq = 0; kq < 256; ++kq) {
        float4 f = *(const float4*)(fb + (kq << 8));
        float4 u = *(const float4*)(w0 + (kq << 2));
        float4 v = *(const float4*)(w1 + (kq << 2));
        float4 s = *(const float4*)(w2 + (kq << 2));
        float4 t = *(const float4*)(w3 + (kq << 2));
        a0 += f.x * u.x + f.y * u.y + f.z * u.z + f.w * u.w;
        a1 += f.x * v.x + f.y * v.y + f.z * v.z + f.w * v.w;
        a2 += f.x * s.x + f.y * s.y + f.z * s.z + f.w * s.w;
        a3 += f.x * t.x + f.y * t.y + f.z * t.z + f.w * t.w;
    }
    red[kh][0][m] = a0; red[kh][1][m] = a1;
    red[kh][2][m] = a2; red[kh][3][m] = a3;
    __syncthreads();
    if (tid < 64) {
#pragma unroll
        for (int c = 0; c < 4; ++c) {
            float v = red[0][c][tid] + red[1][c][tid] + red[2][c][tid] +
                      red[3][c][tid] + hb[n0 + c];
            out[tid * F_OUT_ + n0 + c] = v;
        }
    }
}

extern "C" void kernel_launch(void* const* d_in, const int* in_sizes, int n_in,
                              void* d_out, int out_size, void* d_ws, size_t ws_size,
                              hipStream_t stream) {
    const float* x      = (const float*)d_in[0];
    const float* conv_w = (const float*)d_in[1];
    const float* conv_b = (const float*)d_in[2];
    const float* head_w = (const float*)d_in[3];
    const float* head_b = (const float*)d_in[4];
    float* out   = (float*)d_out;
    float* featQ = (float*)d_ws;                 // 256K floats (1 MB)
    float* mnbuf = featQ + 262144;               // 64b x 64och x 4seg
    float* mxbuf = mnbuf + 16384;                // total ws use ~1.13 MB

    dim3 grid(64, 2, 4);
    conv_mfma_kernel<1><<<grid, 512, 0, stream>>>(x, conv_w, conv_b, featQ, mnbuf, mxbuf);
    conv_mfma_kernel<2><<<grid, 512, 0, stream>>>(x, conv_w, conv_b, featQ, mnbuf, mxbuf);
    head_kernel<<<250, 256, 0, stream>>>(featQ, head_w, head_b, out);
}

// Round 6
// 247.198 us; speedup vs baseline: 1.5537x; 1.0210x over previous
//
#include <hip/hip_runtime.h>

// ---------------------------------------------------------------------------
// MFMA conv3x3(1->64) + per-(b,och) min/max + 64-bin histogram + head.
// conv as 32x32x16 bf16 MFMA: D[m=pixel-row][n=och], k = dr*4+dc
//   (dc=3, dr=3 slots zero-weighted). Split precision x=xh+xl, w=wh+wl:
//   conv = xh*wh + xl*wh + xh*wl (dropped xl*wl ~2^-18 rel).
// A: m=lane&31, k=(lane>>5)*8+j.  B: n=lane&31, same k.
// C: col(n)=lane&31, row(m)=(reg&3)+8*(reg>>2)+4*(lane>>5)   [learn_hip m74]
// LDS tile col-major t32[col*35+row], packed {lo16|hi16} bf16 per pixel.
// R6: kg-divergent row base (no cndmask frag select), column rotation
//   (2 ds_read/col), pass-2 bin transform folded into scaled weights/bias,
//   hist banks spread via och*65 stride with copies 2080 apart.
// ---------------------------------------------------------------------------

typedef short bf16x8 __attribute__((ext_vector_type(8)));
typedef float f32x16 __attribute__((ext_vector_type(16)));

#define TPITCH 35
#define F_OUT_ 1000
#define KDIM_ 4096

__device__ __forceinline__ unsigned f2bf(float f) {   // RNE f32 -> bf16 bits
    unsigned u = __float_as_uint(f);
    return (u + 0x7FFFu + ((u >> 16) & 1u)) >> 16;
}
__device__ __forceinline__ float bf2f(unsigned h) { return __uint_as_float(h << 16); }

union FragU { uint4 u; bf16x8 v; };

template<int PASS>
__global__ __launch_bounds__(512, 4) void conv_mfma_kernel(
    const float* __restrict__ x, const float* __restrict__ cw,
    const float* __restrict__ cb, float* __restrict__ featQ,
    float* __restrict__ mnbuf, float* __restrict__ mxbuf)
{
    // t32: 256 cols x 35 rows = 8960 dwords; aux: hist (pass2, 2*32*65=4160)
    // or wmn/wmx (pass1, 512). Shared region keeps LDS <= 52.5 KB -> 3 blk/CU.
    __shared__ unsigned smem[8960 + 4160];
    unsigned* t32 = smem;
    unsigned* hist = smem + 8960;
    float* wmn = (float*)(smem + 8960);        // pass1 only: [8][32]
    float* wmx = (float*)(smem + 8960 + 256);

    const int tid = threadIdx.x;
    const int lane = tid & 63;
    const int w = __builtin_amdgcn_readfirstlane(tid >> 6);   // wave 0..7
    const int b = blockIdx.x;
    const int ob = blockIdx.y * 32;            // och base
    const int seg = blockIdx.z;                // 64-row segment
    const int mrow = lane & 31;
    const int kg = lane >> 5;

    if (PASS == 1) {   // zero featQ: 512 blocks x 512 = 256K floats exactly
        int z = (seg * 2 + blockIdx.y) * 64 + b;
        featQ[z * 512 + tid] = 0.f;
    }

    // ---- pass2: per-lane (och) bin transform constants ----
    const int och = ob + mrow;
    float sc = 1.f, nls = 0.f;
    if (PASS == 2) {
        float rmn = 3.402823466e38f, rmx = -3.402823466e38f;
#pragma unroll
        for (int s = 0; s < 4; ++s) {
            rmn = fminf(rmn, mnbuf[((b * 64 + och) << 2) | s]);
            rmx = fmaxf(rmx, mxbuf[((b * 64 + och) << 2) | s]);
        }
        float lo = fmaxf(rmn, 0.f);    // relu(min) == min(relu)
        float hi = fmaxf(rmx, 0.f);
        if (hi == lo) { lo -= 1.f; hi += 1.f; }
        sc = 64.f / (hi - lo);
        nls = -lo * sc;
        for (int i = tid; i < 4160; i += 512) hist[i] = 0u;
    }

    // ---- B fragments; pass2 folds sc into weights, nls into bias ----
    float wf[9];
#pragma unroll
    for (int t = 0; t < 9; ++t) wf[t] = cw[och * 9 + t] * ((PASS == 2) ? sc : 1.f);
    unsigned hh[8], ll[8];
#pragma unroll
    for (int j = 0; j < 8; ++j) {
        int k = kg * 8 + j, dr = k >> 2, dc = k & 3;
        float wv = (dr < 3 && dc < 3) ? wf[dr * 3 + dc] : 0.f;
        unsigned h = f2bf(wv);
        hh[j] = h;
        ll[j] = f2bf(wv - bf2f(h));
    }
    FragU bwh, bwl;
    bwh.u = make_uint4(hh[0] | (hh[1] << 16), hh[2] | (hh[3] << 16),
                       hh[4] | (hh[5] << 16), hh[6] | (hh[7] << 16));
    bwl.u = make_uint4(ll[0] | (ll[1] << 16), ll[2] | (ll[3] << 16),
                       ll[4] | (ll[5] << 16), ll[6] | (ll[7] << 16));
    const float bb = (PASS == 2) ? fmaf(cb[och], sc, nls) : cb[och];
    f32x16 cbias;
#pragma unroll
    for (int r = 0; r < 16; ++r) cbias[r] = bb;

    const int hbase = kg * 2080 + mrow * 65;   // copies apart; och spreads banks
    float mn = 3.402823466e38f, mx = -3.402823466e38f;
    const float* xb = x + (size_t)b * 65536;

#pragma unroll 1
    for (int job = 0; job < 2; ++job) {
        const int r0 = seg * 64 + job * 32;
        const int vlim = min(32, 254 - r0);
        __syncthreads();
        // stage rows r0..r0+34 (35 rows: row 34 feeds kg=1 junk slots, must
        // be finite), packed bf16 {lo|hi}, col-major
        for (int i = tid; i < TPITCH * 256; i += 512) {
            int lrow = i >> 8, col = i & 255;
            int grow = r0 + lrow;
            float v = (grow < 256) ? xb[grow * 256 + col] : 0.f;
            unsigned h = f2bf(v);
            unsigned l = f2bf(v - bf2f(h));
            t32[col * TPITCH + lrow] = (l << 16) | h;
        }
        __syncthreads();
        const int cbase = w * 32;
        const int cend = min(cbase + 32, 254);
        // kg-divergent row base: kg=0 reads rows m,m+1 (k 0..7);
        // kg=1 reads rows m+2,m+3 (k 8..11 real, 12..15 zero-weight junk)
        const unsigned* tb = t32 + mrow + 2 * kg;
        unsigned a0 = tb[cbase * TPITCH],       r1a = tb[cbase * TPITCH + 1];
        unsigned a1 = tb[(cbase + 1) * TPITCH], r1b = tb[(cbase + 1) * TPITCH + 1];
#pragma unroll 4
        for (int c = cbase; c < cend; ++c) {
            unsigned a2 = tb[(c + 2) * TPITCH];
            unsigned r1c = tb[(c + 2) * TPITCH + 1];
            FragU ah, al;
            ah.u = make_uint4(__builtin_amdgcn_perm(a1, a0, 0x05040100u), a2,
                              __builtin_amdgcn_perm(r1b, r1a, 0x05040100u), r1c);
            al.u = make_uint4(__builtin_amdgcn_perm(a1, a0, 0x07060302u), a2 >> 16,
                              __builtin_amdgcn_perm(r1b, r1a, 0x07060302u), r1c >> 16);
            a0 = a1; a1 = a2; r1a = r1b; r1b = r1c;
            f32x16 acc = __builtin_amdgcn_mfma_f32_32x32x16_bf16(ah.v, bwh.v, cbias, 0, 0, 0);
            acc = __builtin_amdgcn_mfma_f32_32x32x16_bf16(al.v, bwh.v, acc, 0, 0, 0);
            acc = __builtin_amdgcn_mfma_f32_32x32x16_bf16(ah.v, bwl.v, acc, 0, 0, 0);
            if (PASS == 1) {
                if (vlim >= 32) {
#pragma unroll
                    for (int r = 0; r < 16; r += 2) {
                        mn = fminf(fminf(acc[r], acc[r + 1]), mn);   // v_min3
                        mx = fmaxf(fmaxf(acc[r], acc[r + 1]), mx);
                    }
                } else {
#pragma unroll
                    for (int r = 0; r < 16; ++r) {
                        int crow = (r & 3) + 8 * (r >> 2) + 4 * kg;
                        float v = (crow < vlim) ? acc[r] : acc[0];
                        mn = fminf(mn, v); mx = fmaxf(mx, v);
                    }
                }
            } else {
#pragma unroll
                for (int r = 0; r < 16; ++r) {
                    float t = fminf(fmaxf(acc[r], 0.f), 63.f);   // v_med3 clamp
                    int bin = (int)t;                            // acc IS t (folded)
                    if (vlim < 32) {
                        int crow = (r & 3) + 8 * (r >> 2) + 4 * kg;
                        if (crow >= vlim) bin = 64;              // trash slot
                    }
                    if (bin != 0) atomicAdd(&hist[hbase + bin], 1u);
                }
            }
        }
    }

    if (PASS == 1) {
        mn = fminf(mn, __shfl_xor(mn, 32, 64));
        mx = fmaxf(mx, __shfl_xor(mx, 32, 64));
        __syncthreads();                       // t32/aux reads done everywhere
        if (lane < 32) { wmn[w * 32 + lane] = mn; wmx[w * 32 + lane] = mx; }
        __syncthreads();
        if (tid < 32) {
            float a = wmn[tid], c = wmx[tid];
            for (int i = 1; i < 8; ++i) {
                a = fminf(a, wmn[i * 32 + tid]);
                c = fmaxf(c, wmx[i * 32 + tid]);
            }
            mnbuf[((b * 64 + ob + tid) << 2) | seg] = a;
            mxbuf[((b * 64 + ob + tid) << 2) | seg] = c;
        }
    } else {
        __syncthreads();
        const int validpx = (seg == 3 ? 62 : 64) * 254;
        for (int i = tid; i < 2048; i += 512) {
            int o = i >> 6, bin = i & 63;
            float cnt;
            if (bin == 0) {   // analytic bin0 = validpx - sum(bins 1..63)
                unsigned s = 0;
                for (int j = 1; j < 64; ++j)
                    s += hist[o * 65 + j] + hist[2080 + o * 65 + j];
                cnt = (float)(validpx - (int)s);
            } else {
                cnt = (float)(hist[o * 65 + bin] + hist[2080 + o * 65 + bin]);
            }
            int k = ((ob + o) << 6) | bin;
            // featQ quad layout: featQ[(k>>2)*256 + b*4 + (k&3)]
            atomicAdd(&featQ[((k >> 2) << 8) | (b << 2) | (k & 3)], cnt);
        }
    }
}

// ---------------------------------------------------------------------------
// Head: out[64,1000] = feat @ head_w^T + head_b. 250 blocks x 4 cols;
// 4 waves split K -> featQ read once per block; weights wave-uniform.
// ---------------------------------------------------------------------------
__global__ __launch_bounds__(256) void head_kernel(
    const float* __restrict__ featQ, const float* __restrict__ hw,
    const float* __restrict__ hb, float* __restrict__ out)
{
    __shared__ float red[4][4][64];
    const int tid = threadIdx.x;
    const int m = tid & 63;
    const int kh = __builtin_amdgcn_readfirstlane(tid >> 6);
    const int n0 = blockIdx.x * 4;
    const float* w0 = hw + (size_t)n0 * KDIM_ + kh * 1024;
    const float* w1 = w0 + KDIM_;
    const float* w2 = w1 + KDIM_;
    const float* w3 = w2 + KDIM_;
    const float* fb = featQ + kh * 256 * 256 + (m << 2);

    float a0 = 0.f, a1 = 0.f, a2 = 0.f, a3 = 0.f;
#pragma unroll 4
    for (int kq = 0; kq < 256; ++kq) {
        float4 f = *(const float4*)(fb + (kq << 8));
        float4 u = *(const float4*)(w0 + (kq << 2));
        float4 v = *(const float4*)(w1 + (kq << 2));
        float4 s = *(const float4*)(w2 + (kq << 2));
        float4 t = *(const float4*)(w3 + (kq << 2));
        a0 += f.x * u.x + f.y * u.y + f.z * u.z + f.w * u.w;
        a1 += f.x * v.x + f.y * v.y + f.z * v.z + f.w * v.w;
        a2 += f.x * s.x + f.y * s.y + f.z * s.z + f.w * s.w;
        a3 += f.x * t.x + f.y * t.y + f.z * t.z + f.w * t.w;
    }
    red[kh][0][m] = a0; red[kh][1][m] = a1;
    red[kh][2][m] = a2; red[kh][3][m] = a3;
    __syncthreads();
    if (tid < 64) {
#pragma unroll
        for (int c = 0; c < 4; ++c) {
            float v = red[0][c][tid] + red[1][c][tid] + red[2][c][tid] +
                      red[3][c][tid] + hb[n0 + c];
            out[tid * F_OUT_ + n0 + c] = v;
        }
    }
}

extern "C" void kernel_launch(void* const* d_in, const int* in_sizes, int n_in,
                              void* d_out, int out_size, void* d_ws, size_t ws_size,
                              hipStream_t stream) {
    const float* x      = (const float*)d_in[0];
    const float* conv_w = (const float*)d_in[1];
    const float* conv_b = (const float*)d_in[2];
    const float* head_w = (const float*)d_in[3];
    const float* head_b = (const float*)d_in[4];
    float* out   = (float*)d_out;
    float* featQ = (float*)d_ws;                 // 256K floats (1 MB)
    float* mnbuf = featQ + 262144;
    float* mxbuf = mnbuf + 16384;

    dim3 grid(64, 2, 4);
    conv_mfma_kernel<1><<<grid, 512, 0, stream>>>(x, conv_w, conv_b, featQ, mnbuf, mxbuf);
    conv_mfma_kernel<2><<<grid, 512, 0, stream>>>(x, conv_w, conv_b, featQ, mnbuf, mxbuf);
    head_kernel<<<250, 256, 0, stream>>>(featQ, head_w, head_b, out);
}

// Round 7
// 245.460 us; speedup vs baseline: 1.5647x; 1.0071x over previous
//
#include <hip/hip_runtime.h>

// ---------------------------------------------------------------------------
// MFMA conv3x3(1->64) + per-(b,och) min/max + 64-bin histogram + head.
// conv as 32x32x16 bf16 MFMA, split precision x=xh+xl, w=wh+wl:
//   conv = xh*wh + xl*wh + xh*wl.
// R7: one block computes ALL 64 och (two B-sets, 6 MFMAs share one A),
//   bias injected via K-slot 15 (A=1.0, B=bias) -> C operand is a zero16,
//   pass-2 bin transform folded into B (scaled weights, bias*sc+nls),
//   pk_min/max epilogue in pass 1. Grid 64 batch x 8 row-segments.
// A: m=lane&31, k=(lane>>5)*8+j.  B: n=lane&31.  C: col=lane&31,
//   row=(reg&3)+8*(reg>>2)+4*(lane>>5)  [learn_hip m74/m101]
// LDS tile col-major t32[col*35+row], packed {lo16|hi16} bf16 per pixel.
// ---------------------------------------------------------------------------

typedef short bf16x8 __attribute__((ext_vector_type(8)));
typedef float f32x16 __attribute__((ext_vector_type(16)));
typedef float f32x2 __attribute__((ext_vector_type(2)));

#define TPITCH 35
#define F_OUT_ 1000
#define KDIM_ 4096

__device__ __forceinline__ unsigned f2bf(float f) {   // RNE f32 -> bf16 bits
    unsigned u = __float_as_uint(f);
    return (u + 0x7FFFu + ((u >> 16) & 1u)) >> 16;
}
__device__ __forceinline__ float bf2f(unsigned h) { return __uint_as_float(h << 16); }

union FragU { uint4 u; bf16x8 v; };

template<int PASS>
__global__ __launch_bounds__(512, 4) void conv_mfma_kernel(
    const float* __restrict__ x, const float* __restrict__ cw,
    const float* __restrict__ cb, float* __restrict__ featQ,
    float* __restrict__ mnbuf, float* __restrict__ mxbuf)
{
    __shared__ unsigned t32[256 * TPITCH];     // 8960 dwords
    __shared__ unsigned hist[4 * 32 * 65];     // 8320 dwords (pass2)
    float* wmn = (float*)hist;                 // pass1 overlay: [8][64]
    float* wmx = wmn + 512;

    const int tid = threadIdx.x;
    const int lane = tid & 63;
    const int w = __builtin_amdgcn_readfirstlane(tid >> 6);
    const int b = blockIdx.x;
    const int seg = blockIdx.y;                // 32-row segment (8 total)
    const int mrow = lane & 31;
    const int kg = lane >> 5;
    const int r0 = seg * 32;
    const int vlim = min(32, 254 - r0);        // 32, or 30 for seg 7

    if (PASS == 1)    // zero featQ: 512 blocks x 512 = 256K floats exactly
        featQ[(seg * 64 + b) * 512 + tid] = 0.f;

    // ---- per-group binning constants (pass 2) ----
    const int ochA = mrow, ochB = 32 + mrow;
    float scA = 1.f, nlsA = 0.f, scB = 1.f, nlsB = 0.f;
    if (PASS == 2) {
#pragma unroll
        for (int g = 0; g < 2; ++g) {
            int och = g ? ochB : ochA;
            float rmn = 3.402823466e38f, rmx = -3.402823466e38f;
#pragma unroll
            for (int s = 0; s < 8; ++s) {
                rmn = fminf(rmn, mnbuf[((b * 64 + och) << 3) | s]);
                rmx = fmaxf(rmx, mxbuf[((b * 64 + och) << 3) | s]);
            }
            float lo = fmaxf(rmn, 0.f);        // relu(min) == min(relu)
            float hi = fmaxf(rmx, 0.f);
            if (hi == lo) { lo -= 1.f; hi += 1.f; }
            float sc = 64.f / (hi - lo);
            if (g) { scB = sc; nlsB = -lo * sc; } else { scA = sc; nlsA = -lo * sc; }
        }
        for (int i = tid; i < 4 * 32 * 65; i += 512) hist[i] = 0u;
    }

    // ---- B fragments per group; bias rides k=15 (kg=1, j=7) ----
    FragU bwh[2], bwl[2];
#pragma unroll
    for (int g = 0; g < 2; ++g) {
        int och = g ? ochB : ochA;
        float sc = g ? scB : scA, nls = g ? nlsB : nlsA;
        float wf[9];
#pragma unroll
        for (int t = 0; t < 9; ++t)
            wf[t] = cw[och * 9 + t] * ((PASS == 2) ? sc : 1.f);
        float bias_eff = (PASS == 2) ? fmaf(cb[och], sc, nls) : cb[och];
        unsigned hh[8], ll[8];
#pragma unroll
        for (int j = 0; j < 8; ++j) {
            int k = kg * 8 + j, dr = k >> 2, dc = k & 3;
            float wv = (kg == 1 && j == 7) ? bias_eff
                     : ((dr < 3 && dc < 3) ? wf[dr * 3 + dc] : 0.f);
            unsigned h = f2bf(wv);
            hh[j] = h;
            ll[j] = f2bf(wv - bf2f(h));
        }
        bwh[g].u = make_uint4(hh[0] | (hh[1] << 16), hh[2] | (hh[3] << 16),
                              hh[4] | (hh[5] << 16), hh[6] | (hh[7] << 16));
        bwl[g].u = make_uint4(ll[0] | (ll[1] << 16), ll[2] | (ll[3] << 16),
                              ll[4] | (ll[5] << 16), ll[6] | (ll[7] << 16));
    }
    f32x16 zc;
#pragma unroll
    for (int r = 0; r < 16; ++r) zc[r] = 0.f;

    const float* xb = x + (size_t)b * 65536;

    // ---- stage rows r0..r0+34, packed bf16 {lo|hi}, col-major ----
    __syncthreads();
    for (int i = tid; i < TPITCH * 256; i += 512) {
        int lrow = i >> 8, col = i & 255;
        int grow = r0 + lrow;
        float v = (grow < 256) ? xb[grow * 256 + col] : 0.f;
        unsigned h = f2bf(v);
        unsigned l = f2bf(v - bf2f(h));
        t32[col * TPITCH + lrow] = (l << 16) | h;
    }
    __syncthreads();

    // ---- main column loop: 6 MFMAs share one A-fragment ----
    f32x2 mn2A = {3.4e38f, 3.4e38f}, mx2A = {-3.4e38f, -3.4e38f};
    f32x2 mn2B = {3.4e38f, 3.4e38f}, mx2B = {-3.4e38f, -3.4e38f};
    const int cbase = w * 32;
    const int cend = min(cbase + 32, 254);
    const unsigned* tb = t32 + mrow + 2 * kg;  // kg=0: rows m,m+1; kg=1: m+2,m+3
    unsigned a0 = tb[cbase * TPITCH],       r1a = tb[cbase * TPITCH + 1];
    unsigned a1 = tb[(cbase + 1) * TPITCH], r1b = tb[(cbase + 1) * TPITCH + 1];
#pragma unroll 2
    for (int c = cbase; c < cend; ++c) {
        unsigned a2 = tb[(c + 2) * TPITCH];
        unsigned r1c = tb[(c + 2) * TPITCH + 1];
        FragU ah, al;
        // reg3 high16 = 1.0bf16 at k7 (kg=0, B=0) / k15 (kg=1, B=bias)
        ah.u = make_uint4(__builtin_amdgcn_perm(a1, a0, 0x05040100u), a2,
                          __builtin_amdgcn_perm(r1b, r1a, 0x05040100u),
                          (r1c & 0xFFFFu) | 0x3F800000u);
        al.u = make_uint4(__builtin_amdgcn_perm(a1, a0, 0x07060302u), a2 >> 16,
                          __builtin_amdgcn_perm(r1b, r1a, 0x07060302u), r1c >> 16);
        a0 = a1; a1 = a2; r1a = r1b; r1b = r1c;
        f32x16 accA = __builtin_amdgcn_mfma_f32_32x32x16_bf16(ah.v, bwh[0].v, zc, 0, 0, 0);
        f32x16 accB = __builtin_amdgcn_mfma_f32_32x32x16_bf16(ah.v, bwh[1].v, zc, 0, 0, 0);
        accA = __builtin_amdgcn_mfma_f32_32x32x16_bf16(al.v, bwh[0].v, accA, 0, 0, 0);
        accB = __builtin_amdgcn_mfma_f32_32x32x16_bf16(al.v, bwh[1].v, accB, 0, 0, 0);
        accA = __builtin_amdgcn_mfma_f32_32x32x16_bf16(ah.v, bwl[0].v, accA, 0, 0, 0);
        accB = __builtin_amdgcn_mfma_f32_32x32x16_bf16(ah.v, bwl[1].v, accB, 0, 0, 0);
        if (PASS == 1) {
            if (vlim >= 32) {
#pragma unroll
                for (int r = 0; r < 16; r += 2) {
                    f32x2 vA = {accA[r], accA[r + 1]}, vB = {accB[r], accB[r + 1]};
                    mn2A = __builtin_elementwise_min(mn2A, vA);   // v_pk_min_f32
                    mx2A = __builtin_elementwise_max(mx2A, vA);
                    mn2B = __builtin_elementwise_min(mn2B, vB);
                    mx2B = __builtin_elementwise_max(mx2B, vB);
                }
            } else {
#pragma unroll
                for (int r = 0; r < 16; ++r) {
                    int crow = (r & 3) + 8 * (r >> 2) + 4 * kg;
                    float vA = (crow < vlim) ? accA[r] : accA[0];
                    float vB = (crow < vlim) ? accB[r] : accB[0];
                    mn2A[0] = fminf(mn2A[0], vA); mx2A[0] = fmaxf(mx2A[0], vA);
                    mn2B[0] = fminf(mn2B[0], vB); mx2B[0] = fmaxf(mx2B[0], vB);
                }
            }
        } else {
            const int hbA = (kg * 32 + mrow) * 65;          // group A copies kg
            const int hbB = ((2 + kg) * 32 + mrow) * 65;    // group B copies kg
#pragma unroll
            for (int r = 0; r < 16; ++r) {
                float tA = fminf(fmaxf(accA[r], 0.f), 63.f);  // v_med3 (R2 lesson)
                float tB = fminf(fmaxf(accB[r], 0.f), 63.f);
                int binA = (int)tA, binB = (int)tB;
                if (vlim < 32) {
                    int crow = (r & 3) + 8 * (r >> 2) + 4 * kg;
                    if (crow >= vlim) { binA = 64; binB = 64; }  // trash slot
                }
                if (binA != 0) atomicAdd(&hist[hbA + binA], 1u);
                if (binB != 0) atomicAdd(&hist[hbB + binB], 1u);
            }
        }
    }

    if (PASS == 1) {
        float mnA = fminf(mn2A[0], mn2A[1]), mxA = fmaxf(mx2A[0], mx2A[1]);
        float mnB = fminf(mn2B[0], mn2B[1]), mxB = fmaxf(mx2B[0], mx2B[1]);
        mnA = fminf(mnA, __shfl_xor(mnA, 32, 64));
        mxA = fmaxf(mxA, __shfl_xor(mxA, 32, 64));
        mnB = fminf(mnB, __shfl_xor(mnB, 32, 64));
        mxB = fmaxf(mxB, __shfl_xor(mxB, 32, 64));
        __syncthreads();
        if (lane < 32) {
            wmn[w * 64 + mrow] = mnA;      wmx[w * 64 + mrow] = mxA;
            wmn[w * 64 + 32 + mrow] = mnB; wmx[w * 64 + 32 + mrow] = mxB;
        }
        __syncthreads();
        if (tid < 64) {
            float a = wmn[tid], c = wmx[tid];
#pragma unroll
            for (int i = 1; i < 8; ++i) {
                a = fminf(a, wmn[i * 64 + tid]);
                c = fmaxf(c, wmx[i * 64 + tid]);
            }
            mnbuf[((b * 64 + tid) << 3) | seg] = a;
            mxbuf[((b * 64 + tid) << 3) | seg] = c;
        }
    } else {
        __syncthreads();
        const int validpx = vlim * 254;
        for (int i = tid; i < 4096; i += 512) {
            int och = i >> 6, bin = i & 63;
            int g = och >> 5, o = och & 31;
            int i0 = ((g * 2) * 32 + o) * 65, i1 = ((g * 2 + 1) * 32 + o) * 65;
            float cnt;
            if (bin == 0) {   // analytic bin0 = validpx - sum(bins 1..63)
                unsigned s = 0;
                for (int j = 1; j < 64; ++j) s += hist[i0 + j] + hist[i1 + j];
                cnt = (float)(validpx - (int)s);
            } else {
                cnt = (float)(hist[i0 + bin] + hist[i1 + bin]);
            }
            int k = (och << 6) | bin;
            // featQ quad layout: featQ[(k>>2)*256 + b*4 + (k&3)]
            atomicAdd(&featQ[((k >> 2) << 8) | (b << 2) | (k & 3)], cnt);
        }
    }
}

// ---------------------------------------------------------------------------
// Head: out[64,1000] = feat @ head_w^T + head_b, feat in featQ quad layout.
// 125 blocks x 8 n-cols x 512 threads (m=64 x splitK=8). Each block reads
// featQ exactly once (125 MB L2 total); weights compulsory 16 MB.
// ---------------------------------------------------------------------------
__global__ __launch_bounds__(512) void head_kernel(
    const float* __restrict__ featQ, const float* __restrict__ hw,
    const float* __restrict__ hb, float* __restrict__ out)
{
    __shared__ float red[8][8][64];            // [kh][col][m] 16 KB
    const int tid = threadIdx.x;
    const int m = tid & 63;
    const int kh = __builtin_amdgcn_readfirstlane(tid >> 6);   // K eighth
    const int n0 = blockIdx.x * 8;
    const float* fb = featQ + kh * 128 * 256 + (m << 2);
    const float* wp[8];
#pragma unroll
    for (int c = 0; c < 8; ++c)
        wp[c] = hw + (size_t)(n0 + c) * KDIM_ + kh * 512;

    float a[8] = {0.f, 0.f, 0.f, 0.f, 0.f, 0.f, 0.f, 0.f};
#pragma unroll 2
    for (int kq = 0; kq < 128; ++kq) {
        float4 f = *(const float4*)(fb + (kq << 8));
#pragma unroll
        for (int c = 0; c < 8; ++c) {
            float4 u = *(const float4*)(wp[c] + (kq << 2));
            a[c] += f.x * u.x + f.y * u.y + f.z * u.z + f.w * u.w;
        }
    }
#pragma unroll
    for (int c = 0; c < 8; ++c) red[kh][c][m] = a[c];
    __syncthreads();
    {
        int c = tid >> 6, mm = tid & 63;       // 512 = 8 cols x 64 m
        float v = hb[n0 + c];
#pragma unroll
        for (int q = 0; q < 8; ++q) v += red[q][c][mm];
        out[(size_t)mm * F_OUT_ + n0 + c] = v;
    }
}

extern "C" void kernel_launch(void* const* d_in, const int* in_sizes, int n_in,
                              void* d_out, int out_size, void* d_ws, size_t ws_size,
                              hipStream_t stream) {
    const float* x      = (const float*)d_in[0];
    const float* conv_w = (const float*)d_in[1];
    const float* conv_b = (const float*)d_in[2];
    const float* head_w = (const float*)d_in[3];
    const float* head_b = (const float*)d_in[4];
    float* out   = (float*)d_out;
    float* featQ = (float*)d_ws;                 // 256K floats (1 MB)
    float* mnbuf = featQ + 262144;               // 64*64*8
    float* mxbuf = mnbuf + 32768;                // total ws ~1.31 MB

    dim3 grid(64, 8);
    conv_mfma_kernel<1><<<grid, 512, 0, stream>>>(x, conv_w, conv_b, featQ, mnbuf, mxbuf);
    conv_mfma_kernel<2><<<grid, 512, 0, stream>>>(x, conv_w, conv_b, featQ, mnbuf, mxbuf);
    head_kernel<<<125, 512, 0, stream>>>(featQ, head_w, head_b, out);
}

// Round 8
// 215.575 us; speedup vs baseline: 1.7816x; 1.1386x over previous
//
#include <hip/hip_runtime.h>

// ---------------------------------------------------------------------------
// MFMA conv3x3(1->64) + per-(b,och) min/max + 64-bin histogram + head.
// conv as 32x32x16 bf16 MFMA, split precision x=xh+xl, w=wh+wl:
//   conv = xh*wh + xl*wh + xh*wl.  Bias rides K-slot 15 (A=1.0, B=bias).
// A: m=lane&31, k=(lane>>5)*8+j.  B: n=lane&31.  C: col=lane&31,
//   row=(reg&3)+8*(reg>>2)+4*(lane>>5)  [learn_hip m74/m101]
// LDS tile col-major t32[col*35+row], packed {lo16|hi16} bf16 per pixel.
// R8: passes split into separate kernels (pass1 LDS 40 KB, pass2 52.5 KB ->
//   3 blocks/CU at launch_bounds(512,6)); pass-2 epilogue branchless:
//   bin0 counted in a SINGLE-copy u32 hist (64 och x 65 slots; every lane a
//   distinct och row -> only kg0/kg1 2-way same-address pairs), per value
//   = pk clamp + cvt + lshl_add + ds_add (4 issue slots, was ~10).
// ---------------------------------------------------------------------------

typedef short bf16x8 __attribute__((ext_vector_type(8)));
typedef float f32x16 __attribute__((ext_vector_type(16)));
typedef float f32x2 __attribute__((ext_vector_type(2)));

#define TPITCH 35
#define F_OUT_ 1000
#define KDIM_ 4096

__device__ __forceinline__ unsigned f2bf(float f) {   // RNE f32 -> bf16 bits
    unsigned u = __float_as_uint(f);
    return (u + 0x7FFFu + ((u >> 16) & 1u)) >> 16;
}
__device__ __forceinline__ float bf2f(unsigned h) { return __uint_as_float(h << 16); }

union FragU { uint4 u; bf16x8 v; };

// ---------------- pass 1: conv + min/max --------------------------------
__global__ __launch_bounds__(512, 6) void conv_minmax_kernel(
    const float* __restrict__ x, const float* __restrict__ cw,
    const float* __restrict__ cb, float* __restrict__ featQ,
    float* __restrict__ mnbuf, float* __restrict__ mxbuf)
{
    __shared__ unsigned t32[256 * TPITCH];     // 35840 B
    __shared__ float red[1024];                // wmn[8][64] | wmx[8][64]

    const int tid = threadIdx.x;
    const int lane = tid & 63;
    const int w = __builtin_amdgcn_readfirstlane(tid >> 6);
    const int b = blockIdx.x;
    const int seg = blockIdx.y;
    const int mrow = lane & 31;
    const int kg = lane >> 5;
    const int r0 = seg * 32;
    const int vlim = min(32, 254 - r0);

    // zero featQ: 512 blocks x 512 = 256K floats exactly
    featQ[(seg * 64 + b) * 512 + tid] = 0.f;

    // B fragments (2 och groups); bias at k15
    FragU bwh[2], bwl[2];
#pragma unroll
    for (int g = 0; g < 2; ++g) {
        int och = g * 32 + mrow;
        unsigned hh[8], ll[8];
#pragma unroll
        for (int j = 0; j < 8; ++j) {
            int k = kg * 8 + j, dr = k >> 2, dc = k & 3;
            float wv = (kg == 1 && j == 7) ? cb[och]
                     : ((dr < 3 && dc < 3) ? cw[och * 9 + dr * 3 + dc] : 0.f);
            unsigned h = f2bf(wv);
            hh[j] = h;
            ll[j] = f2bf(wv - bf2f(h));
        }
        bwh[g].u = make_uint4(hh[0] | (hh[1] << 16), hh[2] | (hh[3] << 16),
                              hh[4] | (hh[5] << 16), hh[6] | (hh[7] << 16));
        bwl[g].u = make_uint4(ll[0] | (ll[1] << 16), ll[2] | (ll[3] << 16),
                              ll[4] | (ll[5] << 16), ll[6] | (ll[7] << 16));
    }
    f32x16 zc;
#pragma unroll
    for (int r = 0; r < 16; ++r) zc[r] = 0.f;

    const float* xb = x + (size_t)b * 65536;
    for (int i = tid; i < TPITCH * 256; i += 512) {
        int lrow = i >> 8, col = i & 255;
        int grow = r0 + lrow;
        float v = (grow < 256) ? xb[grow * 256 + col] : 0.f;
        unsigned h = f2bf(v);
        unsigned l = f2bf(v - bf2f(h));
        t32[col * TPITCH + lrow] = (l << 16) | h;
    }
    __syncthreads();

    f32x2 mn2A = {3.4e38f, 3.4e38f}, mx2A = {-3.4e38f, -3.4e38f};
    f32x2 mn2B = {3.4e38f, 3.4e38f}, mx2B = {-3.4e38f, -3.4e38f};
    const int cbase = w * 32;
    const int cend = min(cbase + 32, 254);
    const unsigned* tb = t32 + mrow + 2 * kg;
    unsigned a0 = tb[cbase * TPITCH],       r1a = tb[cbase * TPITCH + 1];
    unsigned a1 = tb[(cbase + 1) * TPITCH], r1b = tb[(cbase + 1) * TPITCH + 1];
#pragma unroll 2
    for (int c = cbase; c < cend; ++c) {
        unsigned a2 = tb[(c + 2) * TPITCH];
        unsigned r1c = tb[(c + 2) * TPITCH + 1];
        FragU ah, al;
        ah.u = make_uint4(__builtin_amdgcn_perm(a1, a0, 0x05040100u), a2,
                          __builtin_amdgcn_perm(r1b, r1a, 0x05040100u),
                          (r1c & 0xFFFFu) | 0x3F800000u);
        al.u = make_uint4(__builtin_amdgcn_perm(a1, a0, 0x07060302u), a2 >> 16,
                          __builtin_amdgcn_perm(r1b, r1a, 0x07060302u), r1c >> 16);
        a0 = a1; a1 = a2; r1a = r1b; r1b = r1c;
        f32x16 accA = __builtin_amdgcn_mfma_f32_32x32x16_bf16(ah.v, bwh[0].v, zc, 0, 0, 0);
        f32x16 accB = __builtin_amdgcn_mfma_f32_32x32x16_bf16(ah.v, bwh[1].v, zc, 0, 0, 0);
        accA = __builtin_amdgcn_mfma_f32_32x32x16_bf16(al.v, bwh[0].v, accA, 0, 0, 0);
        accB = __builtin_amdgcn_mfma_f32_32x32x16_bf16(al.v, bwh[1].v, accB, 0, 0, 0);
        accA = __builtin_amdgcn_mfma_f32_32x32x16_bf16(ah.v, bwl[0].v, accA, 0, 0, 0);
        accB = __builtin_amdgcn_mfma_f32_32x32x16_bf16(ah.v, bwl[1].v, accB, 0, 0, 0);
        if (vlim >= 32) {
#pragma unroll
            for (int r = 0; r < 16; r += 2) {
                f32x2 vA = {accA[r], accA[r + 1]}, vB = {accB[r], accB[r + 1]};
                mn2A = __builtin_elementwise_min(mn2A, vA);
                mx2A = __builtin_elementwise_max(mx2A, vA);
                mn2B = __builtin_elementwise_min(mn2B, vB);
                mx2B = __builtin_elementwise_max(mx2B, vB);
            }
        } else {
#pragma unroll
            for (int r = 0; r < 16; ++r) {
                int crow = (r & 3) + 8 * (r >> 2) + 4 * kg;
                float vA = (crow < vlim) ? accA[r] : accA[0];
                float vB = (crow < vlim) ? accB[r] : accB[0];
                mn2A[0] = fminf(mn2A[0], vA); mx2A[0] = fmaxf(mx2A[0], vA);
                mn2B[0] = fminf(mn2B[0], vB); mx2B[0] = fmaxf(mx2B[0], vB);
            }
        }
    }

    float mnA = fminf(mn2A[0], mn2A[1]), mxA = fmaxf(mx2A[0], mx2A[1]);
    float mnB = fminf(mn2B[0], mn2B[1]), mxB = fmaxf(mx2B[0], mx2B[1]);
    mnA = fminf(mnA, __shfl_xor(mnA, 32, 64));
    mxA = fmaxf(mxA, __shfl_xor(mxA, 32, 64));
    mnB = fminf(mnB, __shfl_xor(mnB, 32, 64));
    mxB = fmaxf(mxB, __shfl_xor(mxB, 32, 64));
    __syncthreads();
    if (lane < 32) {
        red[w * 64 + mrow] = mnA;        red[512 + w * 64 + mrow] = mxA;
        red[w * 64 + 32 + mrow] = mnB;   red[512 + w * 64 + 32 + mrow] = mxB;
    }
    __syncthreads();
    if (tid < 64) {
        float a = red[tid], c = red[512 + tid];
#pragma unroll
        for (int i = 1; i < 8; ++i) {
            a = fminf(a, red[i * 64 + tid]);
            c = fmaxf(c, red[512 + i * 64 + tid]);
        }
        mnbuf[((b * 64 + tid) << 3) | seg] = a;
        mxbuf[((b * 64 + tid) << 3) | seg] = c;
    }
}

// ---------------- pass 2: conv + branchless histogram -------------------
__global__ __launch_bounds__(512, 6) void conv_hist_kernel(
    const float* __restrict__ x, const float* __restrict__ cw,
    const float* __restrict__ cb, float* __restrict__ featQ,
    const float* __restrict__ mnbuf, const float* __restrict__ mxbuf)
{
    __shared__ unsigned t32[256 * TPITCH];     // 35840 B
    __shared__ unsigned hist[64 * 65];         // 16640 B, single copy, bin64=trash

    const int tid = threadIdx.x;
    const int lane = tid & 63;
    const int w = __builtin_amdgcn_readfirstlane(tid >> 6);
    const int b = blockIdx.x;
    const int seg = blockIdx.y;
    const int mrow = lane & 31;
    const int kg = lane >> 5;
    const int r0 = seg * 32;
    const int vlim = min(32, 254 - r0);

    // per-group binning constants from pass-1 min/max
    float scg[2], nlsg[2];
#pragma unroll
    for (int g = 0; g < 2; ++g) {
        int och = g * 32 + mrow;
        float rmn = 3.402823466e38f, rmx = -3.402823466e38f;
#pragma unroll
        for (int s = 0; s < 8; ++s) {
            rmn = fminf(rmn, mnbuf[((b * 64 + och) << 3) | s]);
            rmx = fmaxf(rmx, mxbuf[((b * 64 + och) << 3) | s]);
        }
        float lo = fmaxf(rmn, 0.f);            // relu(min) == min(relu)
        float hi = fmaxf(rmx, 0.f);
        if (hi == lo) { lo -= 1.f; hi += 1.f; }
        scg[g] = 64.f / (hi - lo);
        nlsg[g] = -lo * scg[g];
    }
    for (int i = tid; i < 64 * 65; i += 512) hist[i] = 0u;

    // B fragments, bin transform folded (weights*sc, bias*sc+nls at k15)
    FragU bwh[2], bwl[2];
#pragma unroll
    for (int g = 0; g < 2; ++g) {
        int och = g * 32 + mrow;
        unsigned hh[8], ll[8];
#pragma unroll
        for (int j = 0; j < 8; ++j) {
            int k = kg * 8 + j, dr = k >> 2, dc = k & 3;
            float wv = (kg == 1 && j == 7) ? fmaf(cb[och], scg[g], nlsg[g])
                     : ((dr < 3 && dc < 3) ? cw[och * 9 + dr * 3 + dc] * scg[g] : 0.f);
            unsigned h = f2bf(wv);
            hh[j] = h;
            ll[j] = f2bf(wv - bf2f(h));
        }
        bwh[g].u = make_uint4(hh[0] | (hh[1] << 16), hh[2] | (hh[3] << 16),
                              hh[4] | (hh[5] << 16), hh[6] | (hh[7] << 16));
        bwl[g].u = make_uint4(ll[0] | (ll[1] << 16), ll[2] | (ll[3] << 16),
                              ll[4] | (ll[5] << 16), ll[6] | (ll[7] << 16));
    }
    f32x16 zc;
#pragma unroll
    for (int r = 0; r < 16; ++r) zc[r] = 0.f;

    const float* xb = x + (size_t)b * 65536;
    for (int i = tid; i < TPITCH * 256; i += 512) {
        int lrow = i >> 8, col = i & 255;
        int grow = r0 + lrow;
        float v = (grow < 256) ? xb[grow * 256 + col] : 0.f;
        unsigned h = f2bf(v);
        unsigned l = f2bf(v - bf2f(h));
        t32[col * TPITCH + lrow] = (l << 16) | h;
    }
    __syncthreads();

    const int cbase = w * 32;
    const int cend = min(cbase + 32, 254);
    unsigned* hA = hist + mrow * 65;           // distinct row per lane (+kg pair)
    unsigned* hB = hist + (32 + mrow) * 65;
    const unsigned* tb = t32 + mrow + 2 * kg;
    unsigned a0 = tb[cbase * TPITCH],       r1a = tb[cbase * TPITCH + 1];
    unsigned a1 = tb[(cbase + 1) * TPITCH], r1b = tb[(cbase + 1) * TPITCH + 1];
#pragma unroll 2
    for (int c = cbase; c < cend; ++c) {
        unsigned a2 = tb[(c + 2) * TPITCH];
        unsigned r1c = tb[(c + 2) * TPITCH + 1];
        FragU ah, al;
        ah.u = make_uint4(__builtin_amdgcn_perm(a1, a0, 0x05040100u), a2,
                          __builtin_amdgcn_perm(r1b, r1a, 0x05040100u),
                          (r1c & 0xFFFFu) | 0x3F800000u);
        al.u = make_uint4(__builtin_amdgcn_perm(a1, a0, 0x07060302u), a2 >> 16,
                          __builtin_amdgcn_perm(r1b, r1a, 0x07060302u), r1c >> 16);
        a0 = a1; a1 = a2; r1a = r1b; r1b = r1c;
        f32x16 accA = __builtin_amdgcn_mfma_f32_32x32x16_bf16(ah.v, bwh[0].v, zc, 0, 0, 0);
        f32x16 accB = __builtin_amdgcn_mfma_f32_32x32x16_bf16(ah.v, bwh[1].v, zc, 0, 0, 0);
        accA = __builtin_amdgcn_mfma_f32_32x32x16_bf16(al.v, bwh[0].v, accA, 0, 0, 0);
        accB = __builtin_amdgcn_mfma_f32_32x32x16_bf16(al.v, bwh[1].v, accB, 0, 0, 0);
        accA = __builtin_amdgcn_mfma_f32_32x32x16_bf16(ah.v, bwl[0].v, accA, 0, 0, 0);
        accB = __builtin_amdgcn_mfma_f32_32x32x16_bf16(ah.v, bwl[1].v, accB, 0, 0, 0);
        const f32x2 z2 = {0.f, 0.f}, c2 = {63.f, 63.f};
        if (vlim >= 32) {
#pragma unroll
            for (int r = 0; r < 16; r += 2) {
                f32x2 tA = __builtin_elementwise_min(
                    __builtin_elementwise_max((f32x2){accA[r], accA[r + 1]}, z2), c2);
                f32x2 tB = __builtin_elementwise_min(
                    __builtin_elementwise_max((f32x2){accB[r], accB[r + 1]}, z2), c2);
                atomicAdd(&hA[(int)tA[0]], 1u);
                atomicAdd(&hA[(int)tA[1]], 1u);
                atomicAdd(&hB[(int)tB[0]], 1u);
                atomicAdd(&hB[(int)tB[1]], 1u);
            }
        } else {
#pragma unroll
            for (int r = 0; r < 16; ++r) {
                int crow = (r & 3) + 8 * (r >> 2) + 4 * kg;
                float tA = fminf(fmaxf(accA[r], 0.f), 63.f);
                float tB = fminf(fmaxf(accB[r], 0.f), 63.f);
                int bA = (crow < vlim) ? (int)tA : 64;   // trash slot
                int bB = (crow < vlim) ? (int)tB : 64;
                atomicAdd(&hA[bA], 1u);
                atomicAdd(&hB[bB], 1u);
            }
        }
    }
    __syncthreads();

    // fold hist (bin0 included) into featQ quad layout
    for (int i = tid; i < 4096; i += 512) {
        int och = i >> 6, bin = i & 63;
        float cnt = (float)hist[och * 65 + bin];
        int k = (och << 6) | bin;
        atomicAdd(&featQ[((k >> 2) << 8) | (b << 2) | (k & 3)], cnt);
    }
}

// ---------------------------------------------------------------------------
// Head: out[64,1000] = feat @ head_w^T + head_b, feat in featQ quad layout.
// 125 blocks x 8 n-cols x 512 threads (m=64 x splitK=8).
// ---------------------------------------------------------------------------
__global__ __launch_bounds__(512) void head_kernel(
    const float* __restrict__ featQ, const float* __restrict__ hw,
    const float* __restrict__ hb, float* __restrict__ out)
{
    __shared__ float red[8][8][64];
    const int tid = threadIdx.x;
    const int m = tid & 63;
    const int kh = __builtin_amdgcn_readfirstlane(tid >> 6);
    const int n0 = blockIdx.x * 8;
    const float* fb = featQ + kh * 128 * 256 + (m << 2);
    const float* wp[8];
#pragma unroll
    for (int c = 0; c < 8; ++c)
        wp[c] = hw + (size_t)(n0 + c) * KDIM_ + kh * 512;

    float a[8] = {0.f, 0.f, 0.f, 0.f, 0.f, 0.f, 0.f, 0.f};
#pragma unroll 2
    for (int kq = 0; kq < 128; ++kq) {
        float4 f = *(const float4*)(fb + (kq << 8));
#pragma unroll
        for (int c = 0; c < 8; ++c) {
            float4 u = *(const float4*)(wp[c] + (kq << 2));
            a[c] += f.x * u.x + f.y * u.y + f.z * u.z + f.w * u.w;
        }
    }
#pragma unroll
    for (int c = 0; c < 8; ++c) red[kh][c][m] = a[c];
    __syncthreads();
    {
        int c = tid >> 6, mm = tid & 63;
        float v = hb[n0 + c];
#pragma unroll
        for (int q = 0; q < 8; ++q) v += red[q][c][mm];
        out[(size_t)mm * F_OUT_ + n0 + c] = v;
    }
}

extern "C" void kernel_launch(void* const* d_in, const int* in_sizes, int n_in,
                              void* d_out, int out_size, void* d_ws, size_t ws_size,
                              hipStream_t stream) {
    const float* x      = (const float*)d_in[0];
    const float* conv_w = (const float*)d_in[1];
    const float* conv_b = (const float*)d_in[2];
    const float* head_w = (const float*)d_in[3];
    const float* head_b = (const float*)d_in[4];
    float* out   = (float*)d_out;
    float* featQ = (float*)d_ws;                 // 256K floats (1 MB)
    float* mnbuf = featQ + 262144;               // 64*64*8
    float* mxbuf = mnbuf + 32768;

    dim3 grid(64, 8);
    conv_minmax_kernel<<<grid, 512, 0, stream>>>(x, conv_w, conv_b, featQ, mnbuf, mxbuf);
    conv_hist_kernel<<<grid, 512, 0, stream>>>(x, conv_w, conv_b, featQ, mnbuf, mxbuf);
    head_kernel<<<125, 512, 0, stream>>>(featQ, head_w, head_b, out);
}